// Round 7
// baseline (1035.681 us; speedup 1.0000x reference)
//
#include <hip/hip_runtime.h>

#define B 2
#define NQ 4096
#define NA 2048

typedef __attribute__((ext_vector_type(8))) short bf16x8;
typedef __attribute__((ext_vector_type(4))) float f32x4;

__device__ __forceinline__ float b2f(unsigned short u){ union{unsigned i; float f;} c; c.i=((unsigned)u)<<16; return c.f; }
__device__ __forceinline__ unsigned short f2b(float f){ union{float f; unsigned u;} c; c.f=f; unsigned u=c.u; u += 0x7FFFu + ((u>>16)&1u); return (unsigned short)(u>>16); }
__device__ __forceinline__ void split2(float x, short& h, short& l){
    unsigned short hh = f2b(x); h = (short)hh; l = (short)f2b(x - b2f(hh));
}
__device__ __forceinline__ float4 ld4(const float* p){ return *(const float4*)p; }

// async global->LDS, 16B per lane; LDS dest is wave-uniform base (+lane*16 by HW)
__device__ __forceinline__ void gld_lds16(const void* g, void* s) {
    __builtin_amdgcn_global_load_lds(
        (__attribute__((address_space(1))) unsigned int*)g,
        (__attribute__((address_space(3))) unsigned int*)s,
        16, 0, 0);
}

// ======================= small projections =======================
__global__ __launch_bounds__(256) void proj_small(
    const float* __restrict__ gf,
    const float* __restrict__ w_qs, const float* __restrict__ w_kg, const float* __restrict__ w_vg,
    float* __restrict__ q_attn, float* __restrict__ kgv, float* __restrict__ vgv)
{
    int mat = blockIdx.x >> 1, b = blockIdx.x & 1;
    const float* W = (mat==0) ? w_qs : (mat==1 ? w_kg : w_vg);
    float* O       = (mat==0) ? q_attn : (mat==1 ? kgv : vgv);
    __shared__ float sg[512];
    int t = threadIdx.x;
    for (int i=t;i<512;i+=256) sg[i] = gf[b*512+i];
    __syncthreads();
    for (int c=t;c<512;c+=256) {
        float acc = 0.f;
        for (int k=0;k<512;k++) acc = fmaf(sg[k], W[k*512+c], acc);
        O[b*512+c] = acc;
    }
}

// ============ KNN: register-resident shfl_xor tree merge (verified: 53 us) ============
__global__ __launch_bounds__(256) void knn_kernel(
    const float* __restrict__ xyz_q, const float* __restrict__ axyz, int* __restrict__ knn)
{
    __shared__ float sax[NA], say[NA], saz[NA];   // 24 KB only
    const int t = threadIdx.x;
    const int b  = blockIdx.x >> 9;
    const int qi = t >> 5;
    const int q  = ((blockIdx.x & 511) << 3) + qi;
    const int g  = t & 31;
    for (int i=t;i<NA;i+=256) {
        const float* ap = axyz + (size_t)(b*NA+i)*3;
        sax[i]=ap[0]; say[i]=ap[1]; saz[i]=ap[2];
    }
    __syncthreads();
    const double qx = (double)xyz_q[(size_t)(b*NQ+q)*3+0];
    const double qy = (double)xyz_q[(size_t)(b*NQ+q)*3+1];
    const double qz = (double)xyz_q[(size_t)(b*NQ+q)*3+2];
    const double qq = (qx*qx + qy*qy) + qz*qz;
    double best[8]; int bid[8];
    #pragma unroll
    for (int j=0;j<8;j++){ best[j]=1.0e300; bid[j]=0; }
    for (int jj=0; jj<64; jj++) {
        const int i = jj*32 + g;
        double ax=(double)sax[i], ay=(double)say[i], az=(double)saz[i];
        double aa  = (ax*ax + ay*ay) + az*az;
        double dot = (qx*ax + qy*ay) + qz*az;
        double dd  = (qq + aa) - 2.0*dot;
        if (dd < best[7]) {
            best[7]=dd; bid[7]=i;
            #pragma unroll
            for (int j=7;j>0;--j) if (best[j] < best[j-1]) {
                double tf=best[j]; best[j]=best[j-1]; best[j-1]=tf;
                int ti=bid[j]; bid[j]=bid[j-1]; bid[j-1]=ti;
            }
        }
    }
    #pragma unroll
    for (int s=16; s>=1; s>>=1) {
        double pb[8]; int pbi[8];
        #pragma unroll
        for (int j=0;j<8;j++){
            pb[j]  = __shfl_xor(best[j], s, 64);
            pbi[j] = __shfl_xor(bid[j],  s, 64);
        }
        #pragma unroll
        for (int i=0;i<8;i++) {
            double bo = pb[7-i]; int boi = pbi[7-i];
            if (bo < best[i]) { best[i]=bo; bid[i]=boi; }
        }
        #pragma unroll
        for (int i=0;i<4;i++) {
            if (best[i] > best[i+4]) {
                double td=best[i]; best[i]=best[i+4]; best[i+4]=td;
                int ti=bid[i]; bid[i]=bid[i+4]; bid[i+4]=ti;
            }
        }
        #pragma unroll
        for (int ii=0;ii<2;ii++)
        #pragma unroll
        for (int jj2=0;jj2<2;jj2++) {
            int i = ii*4 + jj2;
            if (best[i] > best[i+2]) {
                double td=best[i]; best[i]=best[i+2]; best[i+2]=td;
                int ti=bid[i]; bid[i]=bid[i+2]; bid[i+2]=ti;
            }
        }
        #pragma unroll
        for (int ii=0;ii<4;ii++) {
            int i = ii*2;
            if (best[i] > best[i+1]) {
                double td=best[i]; best[i]=best[i+1]; best[i+1]=td;
                int ti=bid[i]; bid[i]=bid[i+1]; bid[i+1]=ti;
            }
        }
    }
    if (g == 0) {
        #pragma unroll
        for (int j=0;j<8;j++) knn[(size_t)(b*NQ+q)*8+j] = bid[j];
    }
}

// ======================= weight prep =======================
__global__ __launch_bounds__(256) void prep_w5(
    const float* __restrict__ W0, const float* __restrict__ W1, const float* __restrict__ W2,
    const float* __restrict__ W3, const float* __restrict__ W4,
    short* __restrict__ O0, short* __restrict__ O1, short* __restrict__ O2,
    short* __restrict__ O3, short* __restrict__ O4)
{
    const int m = blockIdx.x >> 7;
    const float* W = (m==0)?W0:(m==1)?W1:(m==2)?W2:(m==3)?W3:W4;
    short* Wb      = (m==0)?O0:(m==1)?O1:(m==2)?O2:(m==3)?O3:O4;
    const int gid = (blockIdx.x & 127)*256 + threadIdx.x;
    const int n  = gid & 511;
    const int kc = (gid >> 9) * 8;
    short o[8];
    #pragma unroll
    for (int j=0;j<8;j++) o[j] = (short)f2b(W[(size_t)(kc+j)*512 + n]);
    *(short4*)&Wb[(size_t)n*512 + kc]     = make_short4(o[0],o[1],o[2],o[3]);
    *(short4*)&Wb[(size_t)n*512 + kc + 4] = make_short4(o[4],o[5],o[6],o[7]);
}
// per-layer prep (small-ws path)
__global__ __launch_bounds__(256) void prep_w3(
    const float* __restrict__ W0, const float* __restrict__ W1, const float* __restrict__ W2,
    short* __restrict__ H0, short* __restrict__ L0,
    short* __restrict__ H1, short* __restrict__ L1,
    short* __restrict__ H2, short* __restrict__ L2)
{
    const int m = blockIdx.x >> 7;
    const float* W = (m==0)?W0:(m==1)?W1:W2;
    short* Wh = (m==0)?H0:(m==1)?H1:H2;
    short* Wl = (m==0)?L0:(m==1)?L1:L2;
    const int gid = (blockIdx.x & 127)*256 + threadIdx.x;
    const int n  = gid & 511;
    const int kc = (gid >> 9) * 8;
    short hi[8], lo[8];
    #pragma unroll
    for (int j=0;j<8;j++) split2(W[(size_t)(kc+j)*512 + n], hi[j], lo[j]);
    *(short4*)&Wh[(size_t)n*512 + kc]     = make_short4(hi[0],hi[1],hi[2],hi[3]);
    *(short4*)&Wh[(size_t)n*512 + kc + 4] = make_short4(hi[4],hi[5],hi[6],hi[7]);
    *(short4*)&Wl[(size_t)n*512 + kc]     = make_short4(lo[0],lo[1],lo[2],lo[3]);
    *(short4*)&Wl[(size_t)n*512 + kc + 4] = make_short4(lo[4],lo[5],lo[6],lo[7]);
}
// all-15-matrices prep (big-ws path)
__global__ __launch_bounds__(256) void prep_w3all(
    const float* __restrict__ CW, const float* __restrict__ B0W, const float* __restrict__ B1W,
    short* __restrict__ DH, short* __restrict__ DL)
{
    const int m = blockIdx.x >> 7;           // 0..14
    const int layer = m / 3, which = m - layer*3;
    const float* W = (which==0 ? CW : which==1 ? B0W : B1W) + (size_t)layer*262144;
    short* Wh = DH + (size_t)m*262144;
    short* Wl = DL + (size_t)m*262144;
    const int gid = (blockIdx.x & 127)*256 + threadIdx.x;
    const int n  = gid & 511;
    const int kc = (gid >> 9) * 8;
    short hi[8], lo[8];
    #pragma unroll
    for (int j=0;j<8;j++) split2(W[(size_t)(kc+j)*512 + n], hi[j], lo[j]);
    *(short4*)&Wh[(size_t)n*512 + kc]     = make_short4(hi[0],hi[1],hi[2],hi[3]);
    *(short4*)&Wh[(size_t)n*512 + kc + 4] = make_short4(hi[4],hi[5],hi[6],hi[7]);
    *(short4*)&Wl[(size_t)n*512 + kc]     = make_short4(lo[0],lo[1],lo[2],lo[3]);
    *(short4*)&Wl[(size_t)n*512 + kc + 4] = make_short4(lo[4],lo[5],lo[6],lo[7]);
}

// ======================= fp32 -> single bf16 =======================
__global__ __launch_bounds__(256) void cvt_bf16(
    const float* __restrict__ X, short* __restrict__ Xb)
{
    const size_t i0 = ((size_t)blockIdx.x*256 + threadIdx.x)*8;
    float4 a = *(const float4*)(X+i0), bq = *(const float4*)(X+i0+4);
    float v[8] = {a.x,a.y,a.z,a.w,bq.x,bq.y,bq.z,bq.w};
    short o[8];
    #pragma unroll
    for (int j=0;j<8;j++) o[j] = (short)f2b(v[j]);
    *(short4*)(Xb+i0)   = make_short4(o[0],o[1],o[2],o[3]);
    *(short4*)(Xb+i0+4) = make_short4(o[4],o[5],o[6],o[7]);
}

// ======== A-materialization: pos-encoder A = relu(d@d1w+d1b), bf16 ========
__global__ __launch_bounds__(256) void pe_make(
    const float* __restrict__ xyz_q, const float* __restrict__ axyz, const int* __restrict__ knn,
    const float* __restrict__ d1w, const float* __restrict__ d1b,
    short* __restrict__ peA, int qbase)
{
    const int t = threadIdx.x;
    const int r  = blockIdx.x*4 + (t >> 6);
    const int col0 = (t & 63) * 8;
    const int gr = qbase*8 + r;
    const int b  = gr >> 15;
    const int gq = gr >> 3;
    const int idx = knn[gr];
    const float* qp = xyz_q + (size_t)gq*3;
    const float* ap = axyz + (size_t)(b*NA + idx)*3;
    const float dx = qp[0]-ap[0], dy = qp[1]-ap[1], dz = qp[2]-ap[2];
    short o[8];
    #pragma unroll
    for (int j=0;j<8;j++) {
        const int k = col0 + j;
        float v = fmaf(dx, d1w[k], fmaf(dy, d1w[512+k], fmaf(dz, d1w[1024+k], d1b[k])));
        o[j] = (short)f2b(fmaxf(v, 0.f));
    }
    *(short4*)&peA[(size_t)r*512 + col0]     = make_short4(o[0],o[1],o[2],o[3]);
    *(short4*)&peA[(size_t)r*512 + col0 + 4] = make_short4(o[4],o[5],o[6],o[7]);
}

// ======== A-materialization: g1 A = q_attn - k + pos, bf16 ========
__global__ __launch_bounds__(256) void g1_make(
    const float* __restrict__ q_attn, const float* __restrict__ kgv,
    const short* __restrict__ ak_bf, const short* __restrict__ pos_bf, const int* __restrict__ knn,
    short* __restrict__ g1A, int qbase)
{
    const int t = threadIdx.x;
    const int r = blockIdx.x*4 + (t >> 6);
    const int col0 = (t & 63) * 8;
    const int b = qbase >> 12;
    const int q = r / 9, n = r - q*9;
    float4 qa0 = ld4(q_attn + b*512 + col0);
    float4 qa1 = ld4(q_attn + b*512 + col0 + 4);
    short o[8];
    if (n < 8) {
        const int ao = b*NA + knn[(size_t)(qbase + q)*8 + n];
        const int po = q*8 + n;
        ushort4 kv0 = *(const ushort4*)(ak_bf + (size_t)ao*512 + col0);
        ushort4 kv1 = *(const ushort4*)(ak_bf + (size_t)ao*512 + col0 + 4);
        ushort4 pv0 = *(const ushort4*)(pos_bf + (size_t)po*512 + col0);
        ushort4 pv1 = *(const ushort4*)(pos_bf + (size_t)po*512 + col0 + 4);
        o[0]=(short)f2b(qa0.x - b2f(kv0.x) + b2f(pv0.x));
        o[1]=(short)f2b(qa0.y - b2f(kv0.y) + b2f(pv0.y));
        o[2]=(short)f2b(qa0.z - b2f(kv0.z) + b2f(pv0.z));
        o[3]=(short)f2b(qa0.w - b2f(kv0.w) + b2f(pv0.w));
        o[4]=(short)f2b(qa1.x - b2f(kv1.x) + b2f(pv1.x));
        o[5]=(short)f2b(qa1.y - b2f(kv1.y) + b2f(pv1.y));
        o[6]=(short)f2b(qa1.z - b2f(kv1.z) + b2f(pv1.z));
        o[7]=(short)f2b(qa1.w - b2f(kv1.w) + b2f(pv1.w));
    } else {
        float4 gk0 = ld4(kgv + b*512 + col0);
        float4 gk1 = ld4(kgv + b*512 + col0 + 4);
        o[0]=(short)f2b(qa0.x - gk0.x); o[1]=(short)f2b(qa0.y - gk0.y);
        o[2]=(short)f2b(qa0.z - gk0.z); o[3]=(short)f2b(qa0.w - gk0.w);
        o[4]=(short)f2b(qa1.x - gk1.x); o[5]=(short)f2b(qa1.y - gk1.y);
        o[6]=(short)f2b(qa1.z - gk1.z); o[7]=(short)f2b(qa1.w - gk1.w);
    }
    *(short4*)&g1A[(size_t)r*512 + col0]     = make_short4(o[0],o[1],o[2],o[3]);
    *(short4*)&g1A[(size_t)r*512 + col0 + 4] = make_short4(o[4],o[5],o[6],o[7]);
}

// ======== x1 GEMM: 128x64 block, 128 thr = 2 waves of 64x64 (0.5 KB LDS-read/MFMA) ========
template<int RELU_OUT>
__global__ __launch_bounds__(128) void gemm1w(
    const short* __restrict__ Ab, const short* __restrict__ Wb,
    const float* __restrict__ bias, short* __restrict__ Cb)
{
    __shared__ short sA[2][128*32], sB[2][64*32];   // 24KB
    const int t = threadIdx.x;
    const int nwg = gridDim.x * gridDim.y;
    const int flat = blockIdx.y * gridDim.x + blockIdx.x;
    const int per = nwg >> 3;
    const int sw = ((nwg & 7) == 0) ? ((flat & 7) * per + (flat >> 3)) : flat;
    const int bx = sw % gridDim.x, by = sw / gridDim.x;
    const int row0 = by * 128, col0 = bx * 64;
    const int lane = t & 63, w = t >> 6;     // 2 waves
    const int m0 = w * 64;                    // wave owns rows m0..m0+63, all 64 cols
    const int fl = lane & 15, quad = lane >> 4;

    f32x4 zero = {0.f,0.f,0.f,0.f};
    f32x4 acc[4][4];
    #pragma unroll
    for (int i=0;i<4;i++)
    #pragma unroll
    for (int j=0;j<4;j++) acc[i][j] = zero;

    auto stage = [&](int buf, int k0) {
        #pragma unroll
        for (int rnd = 0; rnd < 4; ++rnd) {   // A: 128 rows x 32 k
            const int idx = rnd*128 + t;
            const int r = idx >> 2, kp = (idx & 3) * 8;
            const int ldso = (rnd*128 + (t & 64)) * 8;   // shorts, wave-uniform base
            gld_lds16(Ab + (size_t)(row0 + r)*512 + k0 + kp, &sA[buf][ldso]);
        }
        #pragma unroll
        for (int rnd = 0; rnd < 2; ++rnd) {   // B: 64 rows x 32 k
            const int idx = rnd*128 + t;
            const int r = idx >> 2, kp = (idx & 3) * 8;
            const int ldso = (rnd*128 + (t & 64)) * 8;
            gld_lds16(Wb + (size_t)(col0 + r)*512 + k0 + kp, &sB[buf][ldso]);
        }
    };

    stage(0, 0);
    __syncthreads();
    for (int k0 = 0; k0 < 512; k0 += 32) {
        const int cur = (k0 >> 5) & 1;
        if (k0 + 32 < 512) stage(cur ^ 1, k0 + 32);
        bf16x8 fa[4], fb[4];
        #pragma unroll
        for (int i = 0; i < 4; i++) {
            fa[i] = *(const bf16x8*)&sA[cur][(m0 + i*16 + fl)*32 + quad*8];
            fb[i] = *(const bf16x8*)&sB[cur][(i*16 + fl)*32 + quad*8];
        }
        #pragma unroll
        for (int i=0;i<4;i++)
        #pragma unroll
        for (int j=0;j<4;j++)
            acc[i][j] = __builtin_amdgcn_mfma_f32_16x16x32_bf16(fa[i], fb[j], acc[i][j], 0,0,0);
        __syncthreads();
    }
    #pragma unroll
    for (int i=0;i<4;i++)
    #pragma unroll
    for (int j=0;j<4;j++) {
        const int col = col0 + j*16 + fl;
        const float bb = bias ? bias[col] : 0.f;
        #pragma unroll
        for (int r=0;r<4;r++) {
            const int row = row0 + m0 + i*16 + quad*4 + r;
            float v = acc[i][j][r] + bb;
            if (RELU_OUT) v = fmaxf(v, 0.f);
            Cb[(size_t)row*512 + col] = (short)f2b(v);
        }
    }
}

// ======== x3 decoder GEMM: 128x64 block, 2 waves of 64x64, h/l split (0.33 KB/MFMA) ========
// OUT_MODE: 0=fp32; 1=split bf16; 2=fp32 + split(relu(v))
template<int OUT_MODE, int RELU_OUT, int HAS_ADD>
__global__ __launch_bounds__(128) void gemm3w(
    const short* __restrict__ Ah, const short* __restrict__ Al,
    const short* __restrict__ Wh, const short* __restrict__ Wl,
    const float* __restrict__ bias, const float* __restrict__ addend,
    float* __restrict__ Cf, short* __restrict__ Ch, short* __restrict__ Cl)
{
    __shared__ short sAh[2][128*32], sAl[2][128*32], sBh[2][64*32], sBl[2][64*32]; // 48 KB
    const int t = threadIdx.x;
    const int nwg = gridDim.x * gridDim.y;
    const int flat = blockIdx.y * gridDim.x + blockIdx.x;
    const int per = nwg >> 3;
    const int sw = ((nwg & 7) == 0) ? ((flat & 7) * per + (flat >> 3)) : flat;
    const int bx = sw % gridDim.x, by = sw / gridDim.x;
    const int row0 = by * 128, col0 = bx * 64;
    const int lane = t & 63, w = t >> 6;
    const int m0 = w * 64;
    const int fl = lane & 15, quad = lane >> 4;

    f32x4 zero = {0.f,0.f,0.f,0.f};
    f32x4 acc[4][4];
    #pragma unroll
    for (int i=0;i<4;i++)
    #pragma unroll
    for (int j=0;j<4;j++) acc[i][j] = zero;

    auto stage = [&](int buf, int k0) {
        #pragma unroll
        for (int rnd = 0; rnd < 4; ++rnd) {
            const int idx = rnd*128 + t;
            const int r = idx >> 2, kp = (idx & 3) * 8;
            const int ldso = (rnd*128 + (t & 64)) * 8;
            const size_t ga = (size_t)(row0 + r)*512 + k0 + kp;
            gld_lds16(Ah + ga, &sAh[buf][ldso]);
            gld_lds16(Al + ga, &sAl[buf][ldso]);
        }
        #pragma unroll
        for (int rnd = 0; rnd < 2; ++rnd) {
            const int idx = rnd*128 + t;
            const int r = idx >> 2, kp = (idx & 3) * 8;
            const int ldso = (rnd*128 + (t & 64)) * 8;
            const size_t gb = (size_t)(col0 + r)*512 + k0 + kp;
            gld_lds16(Wh + gb, &sBh[buf][ldso]);
            gld_lds16(Wl + gb, &sBl[buf][ldso]);
        }
    };

    stage(0, 0);
    __syncthreads();
    for (int k0 = 0; k0 < 512; k0 += 32) {
        const int cur = (k0 >> 5) & 1;
        if (k0 + 32 < 512) stage(cur ^ 1, k0 + 32);
        bf16x8 fah[4], fal[4], fbh[4], fbl[4];
        #pragma unroll
        for (int i = 0; i < 4; i++) {
            fah[i] = *(const bf16x8*)&sAh[cur][(m0 + i*16 + fl)*32 + quad*8];
            fal[i] = *(const bf16x8*)&sAl[cur][(m0 + i*16 + fl)*32 + quad*8];
            fbh[i] = *(const bf16x8*)&sBh[cur][(i*16 + fl)*32 + quad*8];
            fbl[i] = *(const bf16x8*)&sBl[cur][(i*16 + fl)*32 + quad*8];
        }
        #pragma unroll
        for (int i=0;i<4;i++)
        #pragma unroll
        for (int j=0;j<4;j++)
            acc[i][j] = __builtin_amdgcn_mfma_f32_16x16x32_bf16(fah[i], fbh[j], acc[i][j], 0,0,0);
        #pragma unroll
        for (int i=0;i<4;i++)
        #pragma unroll
        for (int j=0;j<4;j++)
            acc[i][j] = __builtin_amdgcn_mfma_f32_16x16x32_bf16(fah[i], fbl[j], acc[i][j], 0,0,0);
        #pragma unroll
        for (int i=0;i<4;i++)
        #pragma unroll
        for (int j=0;j<4;j++)
            acc[i][j] = __builtin_amdgcn_mfma_f32_16x16x32_bf16(fal[i], fbh[j], acc[i][j], 0,0,0);
        __syncthreads();
    }
    #pragma unroll
    for (int i=0;i<4;i++)
    #pragma unroll
    for (int j=0;j<4;j++) {
        const int col = col0 + j*16 + fl;
        const float bb = bias ? bias[col] : 0.f;
        #pragma unroll
        for (int r=0;r<4;r++) {
            const int row = row0 + m0 + i*16 + quad*4 + r;
            const size_t off = (size_t)row*512 + col;
            float v = acc[i][j][r] + bb;
            if (HAS_ADD) v += addend[off];
            if (OUT_MODE == 0) {
                if (RELU_OUT) v = fmaxf(v,0.f);
                Cf[off] = v;
            } else if (OUT_MODE == 1) {
                if (RELU_OUT) v = fmaxf(v,0.f);
                short h,l; split2(v,h,l); Ch[off]=h; Cl[off]=l;
            } else {
                Cf[off] = v;
                short h,l; split2(fmaxf(v,0.f),h,l); Ch[off]=h; Cl[off]=l;
            }
        }
    }
}

// ======================= softmax + aggregation =======================
__global__ __launch_bounds__(256) void softmax_agg(
    const short* __restrict__ attn_preb, const short* __restrict__ pos_bf,
    const short* __restrict__ av_bf, const float* __restrict__ vgv,
    const int* __restrict__ knn, short* __restrict__ lath, short* __restrict__ latl, int qbase)
{
    __shared__ int sk[8];
    const int q = blockIdx.x;
    const int gq = qbase + q;
    const int b = gq >> 12;
    const int t = threadIdx.x;
    if (t < 8) sk[t] = knn[(size_t)gq*8 + t];
    __syncthreads();
    for (int c = t; c < 512; c += 256) {
        float p[9];
        #pragma unroll
        for (int n=0;n<9;n++) p[n] = b2f((unsigned short)attn_preb[(size_t)(q*9+n)*512 + c]);
        float m = p[0];
        #pragma unroll
        for (int n=1;n<9;n++) m = fmaxf(m, p[n]);
        float e[9], s = 0.f;
        #pragma unroll
        for (int n=0;n<9;n++){ e[n] = expf(p[n]-m); s += e[n]; }
        const float inv = 1.0f / s;
        float acc = 0.f;
        #pragma unroll
        for (int n=0;n<8;n++) {
            float vv = b2f((unsigned short)av_bf[(size_t)(b*NA + sk[n])*512 + c])
                     + b2f((unsigned short)pos_bf[(size_t)(q*8+n)*512 + c]);
            acc = fmaf(e[n]*inv, vv, acc);
        }
        acc = fmaf(e[8]*inv, vgv[b*512 + c], acc);
        short h,l; split2(acc,h,l);
        lath[(size_t)gq*512 + c] = h; latl[(size_t)gq*512 + c] = l;
    }
}

// ======================= PE + first decoder layer =======================
__global__ __launch_bounds__(256) void pe_fc(
    const float* __restrict__ xyz_q, const float* __restrict__ fw, const float* __restrict__ fb,
    float* __restrict__ net)
{
    __shared__ float spe[16*60];
    const int t = threadIdx.x;
    const int q0 = blockIdx.x * 16;
    for (int i=t;i<960;i+=256) {
        int ql = i/60, j = i - ql*60;
        int l = j/6; int r6 = j - l*6; int s = r6/3; int d = r6 - s*3;
        float pv = xyz_q[(size_t)(q0+ql)*3 + d];
        float a = pv * (3.14159265358979323846f * (float)(1<<l));
        spe[ql*60+j] = (s==0) ? sinf(a) : cosf(a);
    }
    __syncthreads();
    float acc0[16], acc1[16];
    #pragma unroll
    for (int ql=0;ql<16;ql++){ acc0[ql]=0.f; acc1[ql]=0.f; }
    const int c0 = t, c1 = t + 256;
    for (int k=0;k<60;k++) {
        float w0 = fw[k*512 + c0];
        float w1 = fw[k*512 + c1];
        #pragma unroll
        for (int ql=0;ql<16;ql++) {
            float pv = spe[ql*60+k];
            acc0[ql] = fmaf(pv, w0, acc0[ql]);
            acc1[ql] = fmaf(pv, w1, acc1[ql]);
        }
    }
    const float b0v = fb[c0], b1v = fb[c1];
    #pragma unroll
    for (int ql=0;ql<16;ql++) {
        net[(size_t)(q0+ql)*512 + c0] = acc0[ql] + b0v;
        net[(size_t)(q0+ql)*512 + c1] = acc1[ql] + b1v;
    }
}

// ======================= launch =======================
extern "C" void kernel_launch(void* const* d_in, const int* in_sizes, int n_in,
                              void* d_out, int out_size, void* d_ws, size_t ws_size,
                              hipStream_t stream) {
    const float* xyz_q  = (const float*)d_in[0];
    const float* gf     = (const float*)d_in[1];
    const float* axyz   = (const float*)d_in[2];
    const float* afeat  = (const float*)d_in[3];
    const float* w_qs   = (const float*)d_in[4];
    const float* w_ks   = (const float*)d_in[5];
    const float* w_vs   = (const float*)d_in[6];
    const float* w_kg   = (const float*)d_in[7];
    const float* w_vg   = (const float*)d_in[8];
    const float* d1_w   = (const float*)d_in[9];
    const float* d1_b   = (const float*)d_in[10];
    const float* d2_w   = (const float*)d_in[11];
    const float* d2_b   = (const float*)d_in[12];
    const float* g1_w   = (const float*)d_in[13];
    const float* g1_b   = (const float*)d_in[14];
    const float* g2_w   = (const float*)d_in[15];
    const float* g2_b   = (const float*)d_in[16];
    const float* fc_p_w = (const float*)d_in[17];
    const float* fc_p_b = (const float*)d_in[18];
    const float* fc_c_w = (const float*)d_in[19];
    const float* fc_c_b = (const float*)d_in[20];
    const float* blk0_w = (const float*)d_in[21];
    const float* blk0_b = (const float*)d_in[22];
    const float* blk1_w = (const float*)d_in[23];
    const float* blk1_b = (const float*)d_in[24];
    float* out = (float*)d_out;

    const size_t MB = 1u<<20;
    char* base = (char*)d_ws;
    const bool big = (ws_size >= (size_t)96*MB);
    const int CHr = big ? 2048 : 1024;
    // ---- persistent (21 MB) ----
    float* q_attn = (float*)base;
    float* kgv    = q_attn + 1024;
    float* vgv    = kgv + 1024;
    int*   knn    = (int*)(base + 16*1024);
    short* wksb = (short*)(base + 1*MB);
    short* wvsb = wksb + 262144;
    short* wd2b = wvsb + 262144;
    short* wg1b = wd2b + 262144;
    short* wg2b = wg1b + 262144;
    short* dch = (short*)(base + 1*MB);         short* dcl = dch + 262144;
    short* d0h = dcl + 262144;                  short* d0l = d0h + 262144;
    short* d1h = d0l + 262144;                  short* d1l = d1h + 262144;
    short* lath = (short*)(base + 5*MB);
    short* latl = (short*)(base + 13*MB);
    // ---- transient T ----
    char* T = base + 21*MB;
    short* ak_bf = (short*)T;                                  // 4 MB
    short* av_bf = (short*)(T + 4*MB);                         // 4 MB
    short* posb  = (short*)(T + 8*MB);                         // CHr*8*512*2
    char*  ybp   = (char*)posb + (size_t)CHr*8*512*2;
    short* yb    = (short*)ybp;                                // CHr*9*512*2
    short* attn_preb = (short*)(ybp + (size_t)CHr*9*512*2);    // CHr*9*512*2
    short* af_bf = (short*)(T + 8*MB);                         // phase A overlay
    short* peA  = attn_preb;
    short* g1A  = attn_preb;
    short* nrh = (short*)T;            short* nrl = (short*)(T + 8*MB);
    short* hdh = (short*)(T + 16*MB);  short* hdl = (short*)(T + 24*MB);
    short* dwH = (short*)(base + 81*MB);
    short* dwL = dwH + (size_t)15*262144;
    if (!big && (size_t)(55*MB) > ws_size) return;

    proj_small<<<dim3(6), dim3(256), 0, stream>>>(gf, w_qs, w_kg, w_vg, q_attn, kgv, vgv);
    knn_kernel<<<dim3(1024), dim3(256), 0, stream>>>(xyz_q, axyz, knn);

    cvt_bf16<<<dim3(1024), dim3(256), 0, stream>>>(afeat, af_bf);
    prep_w5<<<dim3(640), dim3(256), 0, stream>>>(w_ks, w_vs, d2_w, g1_w, g2_w,
                                                 wksb, wvsb, wd2b, wg1b, wg2b);
    gemm1w<0><<<dim3(8, 32), dim3(128), 0, stream>>>(af_bf, wksb, nullptr, ak_bf);
    gemm1w<0><<<dim3(8, 32), dim3(128), 0, stream>>>(af_bf, wvsb, nullptr, av_bf);

    for (int qbase = 0; qbase < B*NQ; qbase += CHr) {
        pe_make<<<dim3(CHr*8/4), dim3(256), 0, stream>>>(xyz_q, axyz, knn, d1_w, d1_b, peA, qbase);
        gemm1w<0><<<dim3(8, CHr*8/128), dim3(128), 0, stream>>>(peA, wd2b, d2_b, posb);
        g1_make<<<dim3(CHr*9/4), dim3(256), 0, stream>>>(q_attn, kgv, ak_bf, posb, knn, g1A, qbase);
        gemm1w<1><<<dim3(8, CHr*9/128), dim3(128), 0, stream>>>(g1A, wg1b, g1_b, yb);
        gemm1w<0><<<dim3(8, CHr*9/128), dim3(128), 0, stream>>>(yb, wg2b, g2_b, attn_preb);
        softmax_agg<<<dim3(CHr), dim3(256), 0, stream>>>(attn_preb, posb, av_bf, vgv, knn, lath, latl, qbase);
    }

    pe_fc<<<dim3(512), dim3(256), 0, stream>>>(xyz_q, fc_p_w, fc_p_b, out);
    if (big) {
        prep_w3all<<<dim3(1920), dim3(256), 0, stream>>>(fc_c_w, blk0_w, blk1_w, dwH, dwL);
        for (int i=0;i<5;i++) {
            const float* cb  = fc_c_b + (size_t)i*512;
            const float* b0b = blk0_b + (size_t)i*512;
            const float* b1b = blk1_b + (size_t)i*512;
            short* ch = dwH + (size_t)(i*3+0)*262144; short* cl = dwL + (size_t)(i*3+0)*262144;
            short* h0 = dwH + (size_t)(i*3+1)*262144; short* l0 = dwL + (size_t)(i*3+1)*262144;
            short* h1 = dwH + (size_t)(i*3+2)*262144; short* l1 = dwL + (size_t)(i*3+2)*262144;
            gemm3w<2,0,1><<<dim3(8,64), dim3(128), 0, stream>>>(lath, latl, ch, cl, cb, out, out, nrh, nrl);
            gemm3w<1,1,0><<<dim3(8,64), dim3(128), 0, stream>>>(nrh, nrl, h0, l0, b0b, nullptr, nullptr, hdh, hdl);
            gemm3w<0,0,1><<<dim3(8,64), dim3(128), 0, stream>>>(hdh, hdl, h1, l1, b1b, out, out, nullptr, nullptr);
        }
    } else {
        for (int i=0;i<5;i++) {
            const float* cw  = fc_c_w + (size_t)i*512*512;
            const float* cb  = fc_c_b + (size_t)i*512;
            const float* b0w = blk0_w + (size_t)i*512*512;
            const float* b0b = blk0_b + (size_t)i*512;
            const float* b1w = blk1_w + (size_t)i*512*512;
            const float* b1b = blk1_b + (size_t)i*512;
            prep_w3<<<dim3(384), dim3(256), 0, stream>>>(cw, b0w, b1w, dch, dcl, d0h, d0l, d1h, d1l);
            gemm3w<2,0,1><<<dim3(8,64), dim3(128), 0, stream>>>(lath, latl, dch, dcl, cb, out, out, nrh, nrl);
            gemm3w<1,1,0><<<dim3(8,64), dim3(128), 0, stream>>>(nrh, nrl, d0h, d0l, b0b, nullptr, nullptr, hdh, hdl);
            gemm3w<0,0,1><<<dim3(8,64), dim3(128), 0, stream>>>(hdh, hdl, d1h, d1l, b1b, out, out, nullptr, nullptr);
        }
    }
}

// Round 8
// 988.641 us; speedup vs baseline: 1.0476x; 1.0476x over previous
//
#include <hip/hip_runtime.h>

#define B 2
#define NQ 4096
#define NA 2048

typedef __attribute__((ext_vector_type(8))) short bf16x8;
typedef __attribute__((ext_vector_type(4))) float f32x4;

__device__ __forceinline__ float b2f(unsigned short u){ union{unsigned i; float f;} c; c.i=((unsigned)u)<<16; return c.f; }
__device__ __forceinline__ unsigned short f2b(float f){ union{float f; unsigned u;} c; c.f=f; unsigned u=c.u; u += 0x7FFFu + ((u>>16)&1u); return (unsigned short)(u>>16); }
__device__ __forceinline__ void split2(float x, short& h, short& l){
    unsigned short hh = f2b(x); h = (short)hh; l = (short)f2b(x - b2f(hh));
}
__device__ __forceinline__ float4 ld4(const float* p){ return *(const float4*)p; }

// async global->LDS, 16B per lane; LDS dest is wave-uniform base (+lane*16 by HW)
__device__ __forceinline__ void gld_lds16(const void* g, void* s) {
    __builtin_amdgcn_global_load_lds(
        (__attribute__((address_space(1))) unsigned int*)g,
        (__attribute__((address_space(3))) unsigned int*)s,
        16, 0, 0);
}

// ======================= small projections =======================
__global__ __launch_bounds__(256) void proj_small(
    const float* __restrict__ gf,
    const float* __restrict__ w_qs, const float* __restrict__ w_kg, const float* __restrict__ w_vg,
    float* __restrict__ q_attn, float* __restrict__ kgv, float* __restrict__ vgv)
{
    int mat = blockIdx.x >> 1, b = blockIdx.x & 1;
    const float* W = (mat==0) ? w_qs : (mat==1 ? w_kg : w_vg);
    float* O       = (mat==0) ? q_attn : (mat==1 ? kgv : vgv);
    __shared__ float sg[512];
    int t = threadIdx.x;
    for (int i=t;i<512;i+=256) sg[i] = gf[b*512+i];
    __syncthreads();
    for (int c=t;c<512;c+=256) {
        float acc = 0.f;
        for (int k=0;k<512;k++) acc = fmaf(sg[k], W[k*512+c], acc);
        O[b*512+c] = acc;
    }
}

// ============ KNN: 4 queries/block x 64 lanes/query, shfl_xor tree merge ============
__global__ __launch_bounds__(256) void knn_kernel(
    const float* __restrict__ xyz_q, const float* __restrict__ axyz, int* __restrict__ knn)
{
    __shared__ float sax[NA], say[NA], saz[NA];   // 24 KB only
    const int t = threadIdx.x;
    const int gq = blockIdx.x*4 + (t >> 6);       // global query, whole wave = one query
    const int b  = gq >> 12;
    const int g  = t & 63;
    for (int i=t;i<NA;i+=256) {
        const float* ap = axyz + (size_t)(b*NA+i)*3;
        sax[i]=ap[0]; say[i]=ap[1]; saz[i]=ap[2];
    }
    __syncthreads();
    const double qx = (double)xyz_q[(size_t)gq*3+0];
    const double qy = (double)xyz_q[(size_t)gq*3+1];
    const double qz = (double)xyz_q[(size_t)gq*3+2];
    const double qq = (qx*qx + qy*qy) + qz*qz;
    double best[8]; int bid[8];
    #pragma unroll
    for (int j=0;j<8;j++){ best[j]=1.0e300; bid[j]=0; }
    for (int jj=0; jj<32; jj++) {
        const int i = jj*64 + g;
        double ax=(double)sax[i], ay=(double)say[i], az=(double)saz[i];
        double aa  = (ax*ax + ay*ay) + az*az;
        double dot = (qx*ax + qy*ay) + qz*az;
        double dd  = (qq + aa) - 2.0*dot;
        if (dd < best[7]) {
            best[7]=dd; bid[7]=i;
            #pragma unroll
            for (int j=7;j>0;--j) if (best[j] < best[j-1]) {
                double tf=best[j]; best[j]=best[j-1]; best[j-1]=tf;
                int ti=bid[j]; bid[j]=bid[j-1]; bid[j-1]=ti;
            }
        }
    }
    // 6-stage tree merge across the 64 lanes of this query, fully in registers.
    #pragma unroll
    for (int s=32; s>=1; s>>=1) {
        double pb[8]; int pbi[8];
        #pragma unroll
        for (int j=0;j<8;j++){
            pb[j]  = __shfl_xor(best[j], s, 64);
            pbi[j] = __shfl_xor(bid[j],  s, 64);
        }
        #pragma unroll
        for (int i=0;i<8;i++) {
            double bo = pb[7-i]; int boi = pbi[7-i];
            if (bo < best[i]) { best[i]=bo; bid[i]=boi; }
        }
        #pragma unroll
        for (int i=0;i<4;i++) {
            if (best[i] > best[i+4]) {
                double td=best[i]; best[i]=best[i+4]; best[i+4]=td;
                int ti=bid[i]; bid[i]=bid[i+4]; bid[i+4]=ti;
            }
        }
        #pragma unroll
        for (int ii=0;ii<2;ii++)
        #pragma unroll
        for (int jj2=0;jj2<2;jj2++) {
            int i = ii*4 + jj2;
            if (best[i] > best[i+2]) {
                double td=best[i]; best[i]=best[i+2]; best[i+2]=td;
                int ti=bid[i]; bid[i]=bid[i+2]; bid[i+2]=ti;
            }
        }
        #pragma unroll
        for (int ii=0;ii<4;ii++) {
            int i = ii*2;
            if (best[i] > best[i+1]) {
                double td=best[i]; best[i]=best[i+1]; best[i+1]=td;
                int ti=bid[i]; bid[i]=bid[i+1]; bid[i+1]=ti;
            }
        }
    }
    if (g == 0) {
        #pragma unroll
        for (int j=0;j<8;j++) knn[(size_t)gq*8+j] = bid[j];
    }
}

// ======================= weight prep =======================
__global__ __launch_bounds__(256) void prep_w5(
    const float* __restrict__ W0, const float* __restrict__ W1, const float* __restrict__ W2,
    const float* __restrict__ W3, const float* __restrict__ W4,
    short* __restrict__ O0, short* __restrict__ O1, short* __restrict__ O2,
    short* __restrict__ O3, short* __restrict__ O4)
{
    const int m = blockIdx.x >> 7;
    const float* W = (m==0)?W0:(m==1)?W1:(m==2)?W2:(m==3)?W3:W4;
    short* Wb      = (m==0)?O0:(m==1)?O1:(m==2)?O2:(m==3)?O3:O4;
    const int gid = (blockIdx.x & 127)*256 + threadIdx.x;
    const int n  = gid & 511;
    const int kc = (gid >> 9) * 8;
    short o[8];
    #pragma unroll
    for (int j=0;j<8;j++) o[j] = (short)f2b(W[(size_t)(kc+j)*512 + n]);
    *(short4*)&Wb[(size_t)n*512 + kc]     = make_short4(o[0],o[1],o[2],o[3]);
    *(short4*)&Wb[(size_t)n*512 + kc + 4] = make_short4(o[4],o[5],o[6],o[7]);
}
// per-layer prep (small-ws path)
__global__ __launch_bounds__(256) void prep_w3(
    const float* __restrict__ W0, const float* __restrict__ W1, const float* __restrict__ W2,
    short* __restrict__ H0, short* __restrict__ L0,
    short* __restrict__ H1, short* __restrict__ L1,
    short* __restrict__ H2, short* __restrict__ L2)
{
    const int m = blockIdx.x >> 7;
    const float* W = (m==0)?W0:(m==1)?W1:W2;
    short* Wh = (m==0)?H0:(m==1)?H1:H2;
    short* Wl = (m==0)?L0:(m==1)?L1:L2;
    const int gid = (blockIdx.x & 127)*256 + threadIdx.x;
    const int n  = gid & 511;
    const int kc = (gid >> 9) * 8;
    short hi[8], lo[8];
    #pragma unroll
    for (int j=0;j<8;j++) split2(W[(size_t)(kc+j)*512 + n], hi[j], lo[j]);
    *(short4*)&Wh[(size_t)n*512 + kc]     = make_short4(hi[0],hi[1],hi[2],hi[3]);
    *(short4*)&Wh[(size_t)n*512 + kc + 4] = make_short4(hi[4],hi[5],hi[6],hi[7]);
    *(short4*)&Wl[(size_t)n*512 + kc]     = make_short4(lo[0],lo[1],lo[2],lo[3]);
    *(short4*)&Wl[(size_t)n*512 + kc + 4] = make_short4(lo[4],lo[5],lo[6],lo[7]);
}
// all-15-matrices prep (big-ws path)
__global__ __launch_bounds__(256) void prep_w3all(
    const float* __restrict__ CW, const float* __restrict__ B0W, const float* __restrict__ B1W,
    short* __restrict__ DH, short* __restrict__ DL)
{
    const int m = blockIdx.x >> 7;           // 0..14
    const int layer = m / 3, which = m - layer*3;
    const float* W = (which==0 ? CW : which==1 ? B0W : B1W) + (size_t)layer*262144;
    short* Wh = DH + (size_t)m*262144;
    short* Wl = DL + (size_t)m*262144;
    const int gid = (blockIdx.x & 127)*256 + threadIdx.x;
    const int n  = gid & 511;
    const int kc = (gid >> 9) * 8;
    short hi[8], lo[8];
    #pragma unroll
    for (int j=0;j<8;j++) split2(W[(size_t)(kc+j)*512 + n], hi[j], lo[j]);
    *(short4*)&Wh[(size_t)n*512 + kc]     = make_short4(hi[0],hi[1],hi[2],hi[3]);
    *(short4*)&Wh[(size_t)n*512 + kc + 4] = make_short4(hi[4],hi[5],hi[6],hi[7]);
    *(short4*)&Wl[(size_t)n*512 + kc]     = make_short4(lo[0],lo[1],lo[2],lo[3]);
    *(short4*)&Wl[(size_t)n*512 + kc + 4] = make_short4(lo[4],lo[5],lo[6],lo[7]);
}

// ======================= fp32 -> single bf16 =======================
__global__ __launch_bounds__(256) void cvt_bf16(
    const float* __restrict__ X, short* __restrict__ Xb)
{
    const size_t i0 = ((size_t)blockIdx.x*256 + threadIdx.x)*8;
    float4 a = *(const float4*)(X+i0), bq = *(const float4*)(X+i0+4);
    float v[8] = {a.x,a.y,a.z,a.w,bq.x,bq.y,bq.z,bq.w};
    short o[8];
    #pragma unroll
    for (int j=0;j<8;j++) o[j] = (short)f2b(v[j]);
    *(short4*)(Xb+i0)   = make_short4(o[0],o[1],o[2],o[3]);
    *(short4*)(Xb+i0+4) = make_short4(o[4],o[5],o[6],o[7]);
}

// ======== A-materialization: pos-encoder A = relu(d@d1w+d1b), bf16 ========
__global__ __launch_bounds__(256) void pe_make(
    const float* __restrict__ xyz_q, const float* __restrict__ axyz, const int* __restrict__ knn,
    const float* __restrict__ d1w, const float* __restrict__ d1b,
    short* __restrict__ peA, int qbase)
{
    const int t = threadIdx.x;
    const int r  = blockIdx.x*4 + (t >> 6);
    const int col0 = (t & 63) * 8;
    const int gr = qbase*8 + r;
    const int b  = gr >> 15;
    const int gq = gr >> 3;
    const int idx = knn[gr];
    const float* qp = xyz_q + (size_t)gq*3;
    const float* ap = axyz + (size_t)(b*NA + idx)*3;
    const float dx = qp[0]-ap[0], dy = qp[1]-ap[1], dz = qp[2]-ap[2];
    short o[8];
    #pragma unroll
    for (int j=0;j<8;j++) {
        const int k = col0 + j;
        float v = fmaf(dx, d1w[k], fmaf(dy, d1w[512+k], fmaf(dz, d1w[1024+k], d1b[k])));
        o[j] = (short)f2b(fmaxf(v, 0.f));
    }
    *(short4*)&peA[(size_t)r*512 + col0]     = make_short4(o[0],o[1],o[2],o[3]);
    *(short4*)&peA[(size_t)r*512 + col0 + 4] = make_short4(o[4],o[5],o[6],o[7]);
}

// ======== A-materialization: g1 A = q_attn - k + pos, bf16 ========
__global__ __launch_bounds__(256) void g1_make(
    const float* __restrict__ q_attn, const float* __restrict__ kgv,
    const short* __restrict__ ak_bf, const short* __restrict__ pos_bf, const int* __restrict__ knn,
    short* __restrict__ g1A, int qbase)
{
    const int t = threadIdx.x;
    const int r = blockIdx.x*4 + (t >> 6);
    const int col0 = (t & 63) * 8;
    const int b = qbase >> 12;
    const int q = r / 9, n = r - q*9;
    float4 qa0 = ld4(q_attn + b*512 + col0);
    float4 qa1 = ld4(q_attn + b*512 + col0 + 4);
    short o[8];
    if (n < 8) {
        const int ao = b*NA + knn[(size_t)(qbase + q)*8 + n];
        const int po = q*8 + n;
        ushort4 kv0 = *(const ushort4*)(ak_bf + (size_t)ao*512 + col0);
        ushort4 kv1 = *(const ushort4*)(ak_bf + (size_t)ao*512 + col0 + 4);
        ushort4 pv0 = *(const ushort4*)(pos_bf + (size_t)po*512 + col0);
        ushort4 pv1 = *(const ushort4*)(pos_bf + (size_t)po*512 + col0 + 4);
        o[0]=(short)f2b(qa0.x - b2f(kv0.x) + b2f(pv0.x));
        o[1]=(short)f2b(qa0.y - b2f(kv0.y) + b2f(pv0.y));
        o[2]=(short)f2b(qa0.z - b2f(kv0.z) + b2f(pv0.z));
        o[3]=(short)f2b(qa0.w - b2f(kv0.w) + b2f(pv0.w));
        o[4]=(short)f2b(qa1.x - b2f(kv1.x) + b2f(pv1.x));
        o[5]=(short)f2b(qa1.y - b2f(kv1.y) + b2f(pv1.y));
        o[6]=(short)f2b(qa1.z - b2f(kv1.z) + b2f(pv1.z));
        o[7]=(short)f2b(qa1.w - b2f(kv1.w) + b2f(pv1.w));
    } else {
        float4 gk0 = ld4(kgv + b*512 + col0);
        float4 gk1 = ld4(kgv + b*512 + col0 + 4);
        o[0]=(short)f2b(qa0.x - gk0.x); o[1]=(short)f2b(qa0.y - gk0.y);
        o[2]=(short)f2b(qa0.z - gk0.z); o[3]=(short)f2b(qa0.w - gk0.w);
        o[4]=(short)f2b(qa1.x - gk1.x); o[5]=(short)f2b(qa1.y - gk1.y);
        o[6]=(short)f2b(qa1.z - gk1.z); o[7]=(short)f2b(qa1.w - gk1.w);
    }
    *(short4*)&g1A[(size_t)r*512 + col0]     = make_short4(o[0],o[1],o[2],o[3]);
    *(short4*)&g1A[(size_t)r*512 + col0 + 4] = make_short4(o[4],o[5],o[6],o[7]);
}

// ======== x1 GEMM: 128x64 tile, global_load_lds, 2-phase dbuf (round-6 verified) ========
template<int RELU_OUT>
__global__ __launch_bounds__(256) void gemm1b(
    const short* __restrict__ Ab, const short* __restrict__ Wb,
    const float* __restrict__ bias, short* __restrict__ Cb)
{
    __shared__ short sA[2][128*32], sB[2][64*32];   // 24KB
    const int t = threadIdx.x;
    const int nwg = gridDim.x * gridDim.y;
    const int flat = blockIdx.y * gridDim.x + blockIdx.x;
    const int per = nwg >> 3;
    const int sw = ((nwg & 7) == 0) ? ((flat & 7) * per + (flat >> 3)) : flat;
    const int bx = sw % gridDim.x, by = sw / gridDim.x;
    const int row0 = by * 128, col0 = bx * 64;
    const int lane = t & 63, w = t >> 6;
    const int m0 = (w >> 1) * 64, n0 = (w & 1) * 32;
    const int fl = lane & 15, quad = lane >> 4;

    f32x4 zero = {0.f,0.f,0.f,0.f};
    f32x4 acc[4][2];
    #pragma unroll
    for (int i=0;i<4;i++)
    #pragma unroll
    for (int j=0;j<2;j++) acc[i][j] = zero;

    auto stage = [&](int buf, int k0) {
        #pragma unroll
        for (int rnd = 0; rnd < 2; ++rnd) {
            const int idx = rnd*256 + t;
            const int r = idx >> 2, kp = (idx & 3) * 8;
            const int ldso = (rnd*256 + (t & 192)) * 8;
            gld_lds16(Ab + (size_t)(row0 + r)*512 + k0 + kp, &sA[buf][ldso]);
        }
        {
            const int r = t >> 2, kp = (t & 3) * 8;
            const int ldso = (t & 192) * 8;
            gld_lds16(Wb + (size_t)(col0 + r)*512 + k0 + kp, &sB[buf][ldso]);
        }
    };

    stage(0, 0);
    __syncthreads();
    for (int k0 = 0; k0 < 512; k0 += 32) {
        const int cur = (k0 >> 5) & 1;
        if (k0 + 32 < 512) stage(cur ^ 1, k0 + 32);
        bf16x8 fa[4], fb[2];
        #pragma unroll
        for (int i = 0; i < 4; i++)
            fa[i] = *(const bf16x8*)&sA[cur][(m0 + i*16 + fl)*32 + quad*8];
        #pragma unroll
        for (int j = 0; j < 2; j++)
            fb[j] = *(const bf16x8*)&sB[cur][(n0 + j*16 + fl)*32 + quad*8];
        #pragma unroll
        for (int i=0;i<4;i++)
        #pragma unroll
        for (int j=0;j<2;j++)
            acc[i][j] = __builtin_amdgcn_mfma_f32_16x16x32_bf16(fa[i], fb[j], acc[i][j], 0,0,0);
        __syncthreads();
    }
    #pragma unroll
    for (int i=0;i<4;i++)
    #pragma unroll
    for (int j=0;j<2;j++) {
        const int col = col0 + n0 + j*16 + fl;
        const float bb = bias ? bias[col] : 0.f;
        #pragma unroll
        for (int r=0;r<4;r++) {
            const int row = row0 + m0 + i*16 + quad*4 + r;
            float v = acc[i][j][r] + bb;
            if (RELU_OUT) v = fmaxf(v, 0.f);
            Cb[(size_t)row*512 + col] = (short)f2b(v);
        }
    }
}

// ======== x3 decoder GEMM: 128x64 tile, global_load_lds, 2-phase dbuf (round-6 verified) ========
// OUT_MODE: 0=fp32; 1=split bf16; 2=fp32 + split(relu(v))
template<int OUT_MODE, int RELU_OUT, int HAS_ADD>
__global__ __launch_bounds__(256) void gemm3b(
    const short* __restrict__ Ah, const short* __restrict__ Al,
    const short* __restrict__ Wh, const short* __restrict__ Wl,
    const float* __restrict__ bias, const float* __restrict__ addend,
    float* __restrict__ Cf, short* __restrict__ Ch, short* __restrict__ Cl)
{
    __shared__ short sAh[2][128*32], sAl[2][128*32], sBh[2][64*32], sBl[2][64*32]; // 48 KB
    const int t = threadIdx.x;
    const int nwg = gridDim.x * gridDim.y;
    const int flat = blockIdx.y * gridDim.x + blockIdx.x;
    const int per = nwg >> 3;
    const int sw = ((nwg & 7) == 0) ? ((flat & 7) * per + (flat >> 3)) : flat;
    const int bx = sw % gridDim.x, by = sw / gridDim.x;
    const int row0 = by * 128, col0 = bx * 64;
    const int lane = t & 63, w = t >> 6;
    const int m0 = (w >> 1) * 64, n0 = (w & 1) * 32;
    const int fl = lane & 15, quad = lane >> 4;

    f32x4 zero = {0.f,0.f,0.f,0.f};
    f32x4 acc[4][2];
    #pragma unroll
    for (int i=0;i<4;i++)
    #pragma unroll
    for (int j=0;j<2;j++) acc[i][j] = zero;

    auto stage = [&](int buf, int k0) {
        #pragma unroll
        for (int rnd = 0; rnd < 2; ++rnd) {
            const int idx = rnd*256 + t;
            const int r = idx >> 2, kp = (idx & 3) * 8;
            const int ldso = (rnd*256 + (t & 192)) * 8;
            const size_t ga = (size_t)(row0 + r)*512 + k0 + kp;
            gld_lds16(Ah + ga, &sAh[buf][ldso]);
            gld_lds16(Al + ga, &sAl[buf][ldso]);
        }
        {
            const int r = t >> 2, kp = (t & 3) * 8;
            const int ldso = (t & 192) * 8;
            const size_t gb = (size_t)(col0 + r)*512 + k0 + kp;
            gld_lds16(Wh + gb, &sBh[buf][ldso]);
            gld_lds16(Wl + gb, &sBl[buf][ldso]);
        }
    };

    stage(0, 0);
    __syncthreads();
    for (int k0 = 0; k0 < 512; k0 += 32) {
        const int cur = (k0 >> 5) & 1;
        if (k0 + 32 < 512) stage(cur ^ 1, k0 + 32);
        bf16x8 fah[4], fal[4], fbh[2], fbl[2];
        #pragma unroll
        for (int i = 0; i < 4; i++) {
            fah[i] = *(const bf16x8*)&sAh[cur][(m0 + i*16 + fl)*32 + quad*8];
            fal[i] = *(const bf16x8*)&sAl[cur][(m0 + i*16 + fl)*32 + quad*8];
        }
        #pragma unroll
        for (int j = 0; j < 2; j++) {
            fbh[j] = *(const bf16x8*)&sBh[cur][(n0 + j*16 + fl)*32 + quad*8];
            fbl[j] = *(const bf16x8*)&sBl[cur][(n0 + j*16 + fl)*32 + quad*8];
        }
        #pragma unroll
        for (int i=0;i<4;i++)
        #pragma unroll
        for (int j=0;j<2;j++)
            acc[i][j] = __builtin_amdgcn_mfma_f32_16x16x32_bf16(fah[i], fbh[j], acc[i][j], 0,0,0);
        #pragma unroll
        for (int i=0;i<4;i++)
        #pragma unroll
        for (int j=0;j<2;j++)
            acc[i][j] = __builtin_amdgcn_mfma_f32_16x16x32_bf16(fah[i], fbl[j], acc[i][j], 0,0,0);
        #pragma unroll
        for (int i=0;i<4;i++)
        #pragma unroll
        for (int j=0;j<2;j++)
            acc[i][j] = __builtin_amdgcn_mfma_f32_16x16x32_bf16(fal[i], fbh[j], acc[i][j], 0,0,0);
        __syncthreads();
    }
    #pragma unroll
    for (int i=0;i<4;i++)
    #pragma unroll
    for (int j=0;j<2;j++) {
        const int col = col0 + n0 + j*16 + fl;
        const float bb = bias ? bias[col] : 0.f;
        #pragma unroll
        for (int r=0;r<4;r++) {
            const int row = row0 + m0 + i*16 + quad*4 + r;
            const size_t off = (size_t)row*512 + col;
            float v = acc[i][j][r] + bb;
            if (HAS_ADD) v += addend[off];
            if (OUT_MODE == 0) {
                if (RELU_OUT) v = fmaxf(v,0.f);
                Cf[off] = v;
            } else if (OUT_MODE == 1) {
                if (RELU_OUT) v = fmaxf(v,0.f);
                short h,l; split2(v,h,l); Ch[off]=h; Cl[off]=l;
            } else {
                Cf[off] = v;
                short h,l; split2(fmaxf(v,0.f),h,l); Ch[off]=h; Cl[off]=l;
            }
        }
    }
}

// ======================= softmax + aggregation =======================
__global__ __launch_bounds__(256) void softmax_agg(
    const short* __restrict__ attn_preb, const short* __restrict__ pos_bf,
    const short* __restrict__ av_bf, const float* __restrict__ vgv,
    const int* __restrict__ knn, short* __restrict__ lath, short* __restrict__ latl, int qbase)
{
    __shared__ int sk[8];
    const int q = blockIdx.x;
    const int gq = qbase + q;
    const int b = gq >> 12;
    const int t = threadIdx.x;
    if (t < 8) sk[t] = knn[(size_t)gq*8 + t];
    __syncthreads();
    for (int c = t; c < 512; c += 256) {
        float p[9];
        #pragma unroll
        for (int n=0;n<9;n++) p[n] = b2f((unsigned short)attn_preb[(size_t)(q*9+n)*512 + c]);
        float m = p[0];
        #pragma unroll
        for (int n=1;n<9;n++) m = fmaxf(m, p[n]);
        float e[9], s = 0.f;
        #pragma unroll
        for (int n=0;n<9;n++){ e[n] = expf(p[n]-m); s += e[n]; }
        const float inv = 1.0f / s;
        float acc = 0.f;
        #pragma unroll
        for (int n=0;n<8;n++) {
            float vv = b2f((unsigned short)av_bf[(size_t)(b*NA + sk[n])*512 + c])
                     + b2f((unsigned short)pos_bf[(size_t)(q*8+n)*512 + c]);
            acc = fmaf(e[n]*inv, vv, acc);
        }
        acc = fmaf(e[8]*inv, vgv[b*512 + c], acc);
        short h,l; split2(acc,h,l);
        lath[(size_t)gq*512 + c] = h; latl[(size_t)gq*512 + c] = l;
    }
}

// ======================= PE + first decoder layer =======================
__global__ __launch_bounds__(256) void pe_fc(
    const float* __restrict__ xyz_q, const float* __restrict__ fw, const float* __restrict__ fb,
    float* __restrict__ net)
{
    __shared__ float spe[16*60];
    const int t = threadIdx.x;
    const int q0 = blockIdx.x * 16;
    for (int i=t;i<960;i+=256) {
        int ql = i/60, j = i - ql*60;
        int l = j/6; int r6 = j - l*6; int s = r6/3; int d = r6 - s*3;
        float pv = xyz_q[(size_t)(q0+ql)*3 + d];
        float a = pv * (3.14159265358979323846f * (float)(1<<l));
        spe[ql*60+j] = (s==0) ? sinf(a) : cosf(a);
    }
    __syncthreads();
    float acc0[16], acc1[16];
    #pragma unroll
    for (int ql=0;ql<16;ql++){ acc0[ql]=0.f; acc1[ql]=0.f; }
    const int c0 = t, c1 = t + 256;
    for (int k=0;k<60;k++) {
        float w0 = fw[k*512 + c0];
        float w1 = fw[k*512 + c1];
        #pragma unroll
        for (int ql=0;ql<16;ql++) {
            float pv = spe[ql*60+k];
            acc0[ql] = fmaf(pv, w0, acc0[ql]);
            acc1[ql] = fmaf(pv, w1, acc1[ql]);
        }
    }
    const float b0v = fb[c0], b1v = fb[c1];
    #pragma unroll
    for (int ql=0;ql<16;ql++) {
        net[(size_t)(q0+ql)*512 + c0] = acc0[ql] + b0v;
        net[(size_t)(q0+ql)*512 + c1] = acc1[ql] + b1v;
    }
}

// ======================= launch =======================
extern "C" void kernel_launch(void* const* d_in, const int* in_sizes, int n_in,
                              void* d_out, int out_size, void* d_ws, size_t ws_size,
                              hipStream_t stream) {
    const float* xyz_q  = (const float*)d_in[0];
    const float* gf     = (const float*)d_in[1];
    const float* axyz   = (const float*)d_in[2];
    const float* afeat  = (const float*)d_in[3];
    const float* w_qs   = (const float*)d_in[4];
    const float* w_ks   = (const float*)d_in[5];
    const float* w_vs   = (const float*)d_in[6];
    const float* w_kg   = (const float*)d_in[7];
    const float* w_vg   = (const float*)d_in[8];
    const float* d1_w   = (const float*)d_in[9];
    const float* d1_b   = (const float*)d_in[10];
    const float* d2_w   = (const float*)d_in[11];
    const float* d2_b   = (const float*)d_in[12];
    const float* g1_w   = (const float*)d_in[13];
    const float* g1_b   = (const float*)d_in[14];
    const float* g2_w   = (const float*)d_in[15];
    const float* g2_b   = (const float*)d_in[16];
    const float* fc_p_w = (const float*)d_in[17];
    const float* fc_p_b = (const float*)d_in[18];
    const float* fc_c_w = (const float*)d_in[19];
    const float* fc_c_b = (const float*)d_in[20];
    const float* blk0_w = (const float*)d_in[21];
    const float* blk0_b = (const float*)d_in[22];
    const float* blk1_w = (const float*)d_in[23];
    const float* blk1_b = (const float*)d_in[24];
    float* out = (float*)d_out;

    const size_t MB = 1u<<20;
    char* base = (char*)d_ws;
    const bool big = (ws_size >= (size_t)96*MB);
    const int CHr = big ? 2048 : 1024;
    // ---- persistent (21 MB) ----
    float* q_attn = (float*)base;
    float* kgv    = q_attn + 1024;
    float* vgv    = kgv + 1024;
    int*   knn    = (int*)(base + 16*1024);
    short* wksb = (short*)(base + 1*MB);
    short* wvsb = wksb + 262144;
    short* wd2b = wvsb + 262144;
    short* wg1b = wd2b + 262144;
    short* wg2b = wg1b + 262144;
    short* dch = (short*)(base + 1*MB);         short* dcl = dch + 262144;
    short* d0h = dcl + 262144;                  short* d0l = d0h + 262144;
    short* d1h = d0l + 262144;                  short* d1l = d1h + 262144;
    short* lath = (short*)(base + 5*MB);
    short* latl = (short*)(base + 13*MB);
    // ---- transient T ----
    char* T = base + 21*MB;
    short* ak_bf = (short*)T;                                  // 4 MB
    short* av_bf = (short*)(T + 4*MB);                         // 4 MB
    short* posb  = (short*)(T + 8*MB);                         // CHr*8*512*2
    char*  ybp   = (char*)posb + (size_t)CHr*8*512*2;
    short* yb    = (short*)ybp;                                // CHr*9*512*2
    short* attn_preb = (short*)(ybp + (size_t)CHr*9*512*2);    // CHr*9*512*2
    short* af_bf = (short*)(T + 8*MB);                         // phase A overlay
    short* peA  = attn_preb;
    short* g1A  = attn_preb;
    short* nrh = (short*)T;            short* nrl = (short*)(T + 8*MB);
    short* hdh = (short*)(T + 16*MB);  short* hdl = (short*)(T + 24*MB);
    short* dwH = (short*)(base + 81*MB);
    short* dwL = dwH + (size_t)15*262144;
    if (!big && (size_t)(55*MB) > ws_size) return;

    proj_small<<<dim3(6), dim3(256), 0, stream>>>(gf, w_qs, w_kg, w_vg, q_attn, kgv, vgv);
    knn_kernel<<<dim3(2048), dim3(256), 0, stream>>>(xyz_q, axyz, knn);

    cvt_bf16<<<dim3(1024), dim3(256), 0, stream>>>(afeat, af_bf);
    prep_w5<<<dim3(640), dim3(256), 0, stream>>>(w_ks, w_vs, d2_w, g1_w, g2_w,
                                                 wksb, wvsb, wd2b, wg1b, wg2b);
    if (big) {
        // hoisted: input-only, writes untouched region; off the decoder critical path
        prep_w3all<<<dim3(1920), dim3(256), 0, stream>>>(fc_c_w, blk0_w, blk1_w, dwH, dwL);
    }
    gemm1b<0><<<dim3(8, 32), dim3(256), 0, stream>>>(af_bf, wksb, nullptr, ak_bf);
    gemm1b<0><<<dim3(8, 32), dim3(256), 0, stream>>>(af_bf, wvsb, nullptr, av_bf);

    for (int qbase = 0; qbase < B*NQ; qbase += CHr) {
        pe_make<<<dim3(CHr*8/4), dim3(256), 0, stream>>>(xyz_q, axyz, knn, d1_w, d1_b, peA, qbase);
        gemm1b<0><<<dim3(8, CHr*8/128), dim3(256), 0, stream>>>(peA, wd2b, d2_b, posb);
        g1_make<<<dim3(CHr*9/4), dim3(256), 0, stream>>>(q_attn, kgv, ak_bf, posb, knn, g1A, qbase);
        gemm1b<1><<<dim3(8, CHr*9/128), dim3(256), 0, stream>>>(g1A, wg1b, g1_b, yb);
        gemm1b<0><<<dim3(8, CHr*9/128), dim3(256), 0, stream>>>(yb, wg2b, g2_b, attn_preb);
        softmax_agg<<<dim3(CHr), dim3(256), 0, stream>>>(attn_preb, posb, av_bf, vgv, knn, lath, latl, qbase);
    }

    pe_fc<<<dim3(512), dim3(256), 0, stream>>>(xyz_q, fc_p_w, fc_p_b, out);
    if (big) {
        for (int i=0;i<5;i++) {
            const float* cb  = fc_c_b + (size_t)i*512;
            const float* b0b = blk0_b + (size_t)i*512;
            const float* b1b = blk1_b + (size_t)i*512;
            short* ch = dwH + (size_t)(i*3+0)*262144; short* cl = dwL + (size_t)(i*3+0)*262144;
            short* h0 = dwH + (size_t)(i*3+1)*262144; short* l0 = dwL + (size_t)(i*3+1)*262144;
            short* h1 = dwH + (size_t)(i*3+2)*262144; short* l1 = dwL + (size_t)(i*3+2)*262144;
            gemm3b<2,0,1><<<dim3(8,64), dim3(256), 0, stream>>>(lath, latl, ch, cl, cb, out, out, nrh, nrl);
            gemm3b<1,1,0><<<dim3(8,64), dim3(256), 0, stream>>>(nrh, nrl, h0, l0, b0b, nullptr, nullptr, hdh, hdl);
            gemm3b<0,0,1><<<dim3(8,64), dim3(256), 0, stream>>>(hdh, hdl, h1, l1, b1b, out, out, nullptr, nullptr);
        }
    } else {
        for (int i=0;i<5;i++) {
            const float* cw  = fc_c_w + (size_t)i*512*512;
            const float* cb  = fc_c_b + (size_t)i*512;
            const float* b0w = blk0_w + (size_t)i*512*512;
            const float* b0b = blk0_b + (size_t)i*512;
            const float* b1w = blk1_w + (size_t)i*512*512;
            const float* b1b = blk1_b + (size_t)i*512;
            prep_w3<<<dim3(384), dim3(256), 0, stream>>>(cw, b0w, b1w, dch, dcl, d0h, d0l, d1h, d1l);
            gemm3b<2,0,1><<<dim3(8,64), dim3(256), 0, stream>>>(lath, latl, dch, dcl, cb, out, out, nrh, nrl);
            gemm3b<1,1,0><<<dim3(8,64), dim3(256), 0, stream>>>(nrh, nrl, d0h, d0l, b0b, nullptr, nullptr, hdh, hdl);
            gemm3b<0,0,1><<<dim3(8,64), dim3(256), 0, stream>>>(hdh, hdl, d1h, d1l, b1b, out, out, nullptr, nullptr);
        }
    }
}

// Round 10
// 976.794 us; speedup vs baseline: 1.0603x; 1.0121x over previous
//
#include <hip/hip_runtime.h>

#define B 2
#define NQ 4096
#define NA 2048

typedef __attribute__((ext_vector_type(8))) short bf16x8;
typedef __attribute__((ext_vector_type(4))) float f32x4;

__device__ __forceinline__ float b2f(unsigned short u){ union{unsigned i; float f;} c; c.i=((unsigned)u)<<16; return c.f; }
__device__ __forceinline__ unsigned short f2b(float f){ union{float f; unsigned u;} c; c.f=f; unsigned u=c.u; u += 0x7FFFu + ((u>>16)&1u); return (unsigned short)(u>>16); }
__device__ __forceinline__ void split2(float x, short& h, short& l){
    unsigned short hh = f2b(x); h = (short)hh; l = (short)f2b(x - b2f(hh));
}
__device__ __forceinline__ float4 ld4(const float* p){ return *(const float4*)p; }

// async global->LDS, 16B per lane; LDS dest is wave-uniform base (+lane*16 by HW)
__device__ __forceinline__ void gld_lds16(const void* g, void* s) {
    __builtin_amdgcn_global_load_lds(
        (__attribute__((address_space(1))) unsigned int*)g,
        (__attribute__((address_space(3))) unsigned int*)s,
        16, 0, 0);
}

// ======================= small projections =======================
__global__ __launch_bounds__(256) void proj_small(
    const float* __restrict__ gf,
    const float* __restrict__ w_qs, const float* __restrict__ w_kg, const float* __restrict__ w_vg,
    float* __restrict__ q_attn, float* __restrict__ kgv, float* __restrict__ vgv)
{
    int mat = blockIdx.x >> 1, b = blockIdx.x & 1;
    const float* W = (mat==0) ? w_qs : (mat==1 ? w_kg : w_vg);
    float* O       = (mat==0) ? q_attn : (mat==1 ? kgv : vgv);
    __shared__ float sg[512];
    int t = threadIdx.x;
    for (int i=t;i<512;i+=256) sg[i] = gf[b*512+i];
    __syncthreads();
    for (int c=t;c<512;c+=256) {
        float acc = 0.f;
        for (int k=0;k<512;k++) acc = fmaf(sg[k], W[k*512+c], acc);
        O[b*512+c] = acc;
    }
}

// ============ KNN: f64 distances (load-bearing for neighbor ordering), 8q x 32 lanes,
// register-resident shfl_xor bitonic tree merge (verified 52-53 us, rounds 6-7) ============
__global__ __launch_bounds__(256) void knn_kernel(
    const float* __restrict__ xyz_q, const float* __restrict__ axyz, int* __restrict__ knn)
{
    __shared__ float sax[NA], say[NA], saz[NA];   // 24 KB only
    const int t = threadIdx.x;
    const int b  = blockIdx.x >> 9;
    const int qi = t >> 5;
    const int q  = ((blockIdx.x & 511) << 3) + qi;
    const int g  = t & 31;
    for (int i=t;i<NA;i+=256) {
        const float* ap = axyz + (size_t)(b*NA+i)*3;
        sax[i]=ap[0]; say[i]=ap[1]; saz[i]=ap[2];
    }
    __syncthreads();
    const double qx = (double)xyz_q[(size_t)(b*NQ+q)*3+0];
    const double qy = (double)xyz_q[(size_t)(b*NQ+q)*3+1];
    const double qz = (double)xyz_q[(size_t)(b*NQ+q)*3+2];
    const double qq = (qx*qx + qy*qy) + qz*qz;
    double best[8]; int bid[8];
    #pragma unroll
    for (int j=0;j<8;j++){ best[j]=1.0e300; bid[j]=0; }
    for (int jj=0; jj<64; jj++) {
        const int i = jj*32 + g;
        double ax=(double)sax[i], ay=(double)say[i], az=(double)saz[i];
        double aa  = (ax*ax + ay*ay) + az*az;
        double dot = (qx*ax + qy*ay) + qz*az;
        double dd  = (qq + aa) - 2.0*dot;
        if (dd < best[7]) {
            best[7]=dd; bid[7]=i;
            #pragma unroll
            for (int j=7;j>0;--j) if (best[j] < best[j-1]) {
                double tf=best[j]; best[j]=best[j-1]; best[j-1]=tf;
                int ti=bid[j]; bid[j]=bid[j-1]; bid[j-1]=ti;
            }
        }
    }
    // 5-stage tree merge across the 32 lanes of this query, fully in registers.
    #pragma unroll
    for (int s=16; s>=1; s>>=1) {
        double pb[8]; int pbi[8];
        #pragma unroll
        for (int j=0;j<8;j++){
            pb[j]  = __shfl_xor(best[j], s, 64);
            pbi[j] = __shfl_xor(bid[j],  s, 64);
        }
        #pragma unroll
        for (int i=0;i<8;i++) {
            double bo = pb[7-i]; int boi = pbi[7-i];
            if (bo < best[i]) { best[i]=bo; bid[i]=boi; }
        }
        #pragma unroll
        for (int i=0;i<4;i++) {
            if (best[i] > best[i+4]) {
                double td=best[i]; best[i]=best[i+4]; best[i+4]=td;
                int ti=bid[i]; bid[i]=bid[i+4]; bid[i+4]=ti;
            }
        }
        #pragma unroll
        for (int ii=0;ii<2;ii++)
        #pragma unroll
        for (int jj2=0;jj2<2;jj2++) {
            int i = ii*4 + jj2;
            if (best[i] > best[i+2]) {
                double td=best[i]; best[i]=best[i+2]; best[i+2]=td;
                int ti=bid[i]; bid[i]=bid[i+2]; bid[i+2]=ti;
            }
        }
        #pragma unroll
        for (int ii=0;ii<4;ii++) {
            int i = ii*2;
            if (best[i] > best[i+1]) {
                double td=best[i]; best[i]=best[i+1]; best[i+1]=td;
                int ti=bid[i]; bid[i]=bid[i+1]; bid[i+1]=ti;
            }
        }
    }
    if (g == 0) {
        #pragma unroll
        for (int j=0;j<8;j++) knn[(size_t)(b*NQ+q)*8+j] = bid[j];
    }
}

// ======================= weight prep =======================
__global__ __launch_bounds__(256) void prep_w5(
    const float* __restrict__ W0, const float* __restrict__ W1, const float* __restrict__ W2,
    const float* __restrict__ W3, const float* __restrict__ W4,
    short* __restrict__ O0, short* __restrict__ O1, short* __restrict__ O2,
    short* __restrict__ O3, short* __restrict__ O4)
{
    const int m = blockIdx.x >> 7;
    const float* W = (m==0)?W0:(m==1)?W1:(m==2)?W2:(m==3)?W3:W4;
    short* Wb      = (m==0)?O0:(m==1)?O1:(m==2)?O2:(m==3)?O3:O4;
    const int gid = (blockIdx.x & 127)*256 + threadIdx.x;
    const int n  = gid & 511;
    const int kc = (gid >> 9) * 8;
    short o[8];
    #pragma unroll
    for (int j=0;j<8;j++) o[j] = (short)f2b(W[(size_t)(kc+j)*512 + n]);
    *(short4*)&Wb[(size_t)n*512 + kc]     = make_short4(o[0],o[1],o[2],o[3]);
    *(short4*)&Wb[(size_t)n*512 + kc + 4] = make_short4(o[4],o[5],o[6],o[7]);
}
// per-layer prep (small-ws path)
__global__ __launch_bounds__(256) void prep_w3(
    const float* __restrict__ W0, const float* __restrict__ W1, const float* __restrict__ W2,
    short* __restrict__ H0, short* __restrict__ L0,
    short* __restrict__ H1, short* __restrict__ L1,
    short* __restrict__ H2, short* __restrict__ L2)
{
    const int m = blockIdx.x >> 7;
    const float* W = (m==0)?W0:(m==1)?W1:W2;
    short* Wh = (m==0)?H0:(m==1)?H1:H2;
    short* Wl = (m==0)?L0:(m==1)?L1:L2;
    const int gid = (blockIdx.x & 127)*256 + threadIdx.x;
    const int n  = gid & 511;
    const int kc = (gid >> 9) * 8;
    short hi[8], lo[8];
    #pragma unroll
    for (int j=0;j<8;j++) split2(W[(size_t)(kc+j)*512 + n], hi[j], lo[j]);
    *(short4*)&Wh[(size_t)n*512 + kc]     = make_short4(hi[0],hi[1],hi[2],hi[3]);
    *(short4*)&Wh[(size_t)n*512 + kc + 4] = make_short4(hi[4],hi[5],hi[6],hi[7]);
    *(short4*)&Wl[(size_t)n*512 + kc]     = make_short4(lo[0],lo[1],lo[2],lo[3]);
    *(short4*)&Wl[(size_t)n*512 + kc + 4] = make_short4(lo[4],lo[5],lo[6],lo[7]);
}
// all-15-matrices prep (big-ws path)
__global__ __launch_bounds__(256) void prep_w3all(
    const float* __restrict__ CW, const float* __restrict__ B0W, const float* __restrict__ B1W,
    short* __restrict__ DH, short* __restrict__ DL)
{
    const int m = blockIdx.x >> 7;           // 0..14
    const int layer = m / 3, which = m - layer*3;
    const float* W = (which==0 ? CW : which==1 ? B0W : B1W) + (size_t)layer*262144;
    short* Wh = DH + (size_t)m*262144;
    short* Wl = DL + (size_t)m*262144;
    const int gid = (blockIdx.x & 127)*256 + threadIdx.x;
    const int n  = gid & 511;
    const int kc = (gid >> 9) * 8;
    short hi[8], lo[8];
    #pragma unroll
    for (int j=0;j<8;j++) split2(W[(size_t)(kc+j)*512 + n], hi[j], lo[j]);
    *(short4*)&Wh[(size_t)n*512 + kc]     = make_short4(hi[0],hi[1],hi[2],hi[3]);
    *(short4*)&Wh[(size_t)n*512 + kc + 4] = make_short4(hi[4],hi[5],hi[6],hi[7]);
    *(short4*)&Wl[(size_t)n*512 + kc]     = make_short4(lo[0],lo[1],lo[2],lo[3]);
    *(short4*)&Wl[(size_t)n*512 + kc + 4] = make_short4(lo[4],lo[5],lo[6],lo[7]);
}

// ======================= fp32 -> single bf16 =======================
__global__ __launch_bounds__(256) void cvt_bf16(
    const float* __restrict__ X, short* __restrict__ Xb)
{
    const size_t i0 = ((size_t)blockIdx.x*256 + threadIdx.x)*8;
    float4 a = *(const float4*)(X+i0), bq = *(const float4*)(X+i0+4);
    float v[8] = {a.x,a.y,a.z,a.w,bq.x,bq.y,bq.z,bq.w};
    short o[8];
    #pragma unroll
    for (int j=0;j<8;j++) o[j] = (short)f2b(v[j]);
    *(short4*)(Xb+i0)   = make_short4(o[0],o[1],o[2],o[3]);
    *(short4*)(Xb+i0+4) = make_short4(o[4],o[5],o[6],o[7]);
}

// ======== A-materialization: pos-encoder A = relu(d@d1w+d1b), bf16 ========
__global__ __launch_bounds__(256) void pe_make(
    const float* __restrict__ xyz_q, const float* __restrict__ axyz, const int* __restrict__ knn,
    const float* __restrict__ d1w, const float* __restrict__ d1b,
    short* __restrict__ peA, int qbase)
{
    const int t = threadIdx.x;
    const int r  = blockIdx.x*4 + (t >> 6);
    const int col0 = (t & 63) * 8;
    const int gr = qbase*8 + r;
    const int b  = gr >> 15;
    const int gq = gr >> 3;
    const int idx = knn[gr];
    const float* qp = xyz_q + (size_t)gq*3;
    const float* ap = axyz + (size_t)(b*NA + idx)*3;
    const float dx = qp[0]-ap[0], dy = qp[1]-ap[1], dz = qp[2]-ap[2];
    short o[8];
    #pragma unroll
    for (int j=0;j<8;j++) {
        const int k = col0 + j;
        float v = fmaf(dx, d1w[k], fmaf(dy, d1w[512+k], fmaf(dz, d1w[1024+k], d1b[k])));
        o[j] = (short)f2b(fmaxf(v, 0.f));
    }
    *(short4*)&peA[(size_t)r*512 + col0]     = make_short4(o[0],o[1],o[2],o[3]);
    *(short4*)&peA[(size_t)r*512 + col0 + 4] = make_short4(o[4],o[5],o[6],o[7]);
}

// ======== A-materialization: g1 A = q_attn - k + pos, bf16 ========
__global__ __launch_bounds__(256) void g1_make(
    const float* __restrict__ q_attn, const float* __restrict__ kgv,
    const short* __restrict__ ak_bf, const short* __restrict__ pos_bf, const int* __restrict__ knn,
    short* __restrict__ g1A, int qbase)
{
    const int t = threadIdx.x;
    const int r = blockIdx.x*4 + (t >> 6);
    const int col0 = (t & 63) * 8;
    const int b = qbase >> 12;
    const int q = r / 9, n = r - q*9;
    float4 qa0 = ld4(q_attn + b*512 + col0);
    float4 qa1 = ld4(q_attn + b*512 + col0 + 4);
    short o[8];
    if (n < 8) {
        const int ao = b*NA + knn[(size_t)(qbase + q)*8 + n];
        const int po = q*8 + n;
        ushort4 kv0 = *(const ushort4*)(ak_bf + (size_t)ao*512 + col0);
        ushort4 kv1 = *(const ushort4*)(ak_bf + (size_t)ao*512 + col0 + 4);
        ushort4 pv0 = *(const ushort4*)(pos_bf + (size_t)po*512 + col0);
        ushort4 pv1 = *(const ushort4*)(pos_bf + (size_t)po*512 + col0 + 4);
        o[0]=(short)f2b(qa0.x - b2f(kv0.x) + b2f(pv0.x));
        o[1]=(short)f2b(qa0.y - b2f(kv0.y) + b2f(pv0.y));
        o[2]=(short)f2b(qa0.z - b2f(kv0.z) + b2f(pv0.z));
        o[3]=(short)f2b(qa0.w - b2f(kv0.w) + b2f(pv0.w));
        o[4]=(short)f2b(qa1.x - b2f(kv1.x) + b2f(pv1.x));
        o[5]=(short)f2b(qa1.y - b2f(kv1.y) + b2f(pv1.y));
        o[6]=(short)f2b(qa1.z - b2f(kv1.z) + b2f(pv1.z));
        o[7]=(short)f2b(qa1.w - b2f(kv1.w) + b2f(pv1.w));
    } else {
        float4 gk0 = ld4(kgv + b*512 + col0);
        float4 gk1 = ld4(kgv + b*512 + col0 + 4);
        o[0]=(short)f2b(qa0.x - gk0.x); o[1]=(short)f2b(qa0.y - gk0.y);
        o[2]=(short)f2b(qa0.z - gk0.z); o[3]=(short)f2b(qa0.w - gk0.w);
        o[4]=(short)f2b(qa1.x - gk1.x); o[5]=(short)f2b(qa1.y - gk1.y);
        o[6]=(short)f2b(qa1.z - gk1.z); o[7]=(short)f2b(qa1.w - gk1.w);
    }
    *(short4*)&g1A[(size_t)r*512 + col0]     = make_short4(o[0],o[1],o[2],o[3]);
    *(short4*)&g1A[(size_t)r*512 + col0 + 4] = make_short4(o[4],o[5],o[6],o[7]);
}

// ======== x1 GEMM: 128x64 tile, global_load_lds, 2-phase dbuf (round-6 verified) ========
template<int RELU_OUT>
__global__ __launch_bounds__(256) void gemm1b(
    const short* __restrict__ Ab, const short* __restrict__ Wb,
    const float* __restrict__ bias, short* __restrict__ Cb)
{
    __shared__ short sA[2][128*32], sB[2][64*32];   // 24KB
    const int t = threadIdx.x;
    const int nwg = gridDim.x * gridDim.y;
    const int flat = blockIdx.y * gridDim.x + blockIdx.x;
    const int per = nwg >> 3;
    const int sw = ((nwg & 7) == 0) ? ((flat & 7) * per + (flat >> 3)) : flat;
    const int bx = sw % gridDim.x, by = sw / gridDim.x;
    const int row0 = by * 128, col0 = bx * 64;
    const int lane = t & 63, w = t >> 6;
    const int m0 = (w >> 1) * 64, n0 = (w & 1) * 32;
    const int fl = lane & 15, quad = lane >> 4;

    f32x4 zero = {0.f,0.f,0.f,0.f};
    f32x4 acc[4][2];
    #pragma unroll
    for (int i=0;i<4;i++)
    #pragma unroll
    for (int j=0;j<2;j++) acc[i][j] = zero;

    auto stage = [&](int buf, int k0) {
        #pragma unroll
        for (int rnd = 0; rnd < 2; ++rnd) {
            const int idx = rnd*256 + t;
            const int r = idx >> 2, kp = (idx & 3) * 8;
            const int ldso = (rnd*256 + (t & 192)) * 8;
            gld_lds16(Ab + (size_t)(row0 + r)*512 + k0 + kp, &sA[buf][ldso]);
        }
        {
            const int r = t >> 2, kp = (t & 3) * 8;
            const int ldso = (t & 192) * 8;
            gld_lds16(Wb + (size_t)(col0 + r)*512 + k0 + kp, &sB[buf][ldso]);
        }
    };

    stage(0, 0);
    __syncthreads();
    for (int k0 = 0; k0 < 512; k0 += 32) {
        const int cur = (k0 >> 5) & 1;
        if (k0 + 32 < 512) stage(cur ^ 1, k0 + 32);
        bf16x8 fa[4], fb[2];
        #pragma unroll
        for (int i = 0; i < 4; i++)
            fa[i] = *(const bf16x8*)&sA[cur][(m0 + i*16 + fl)*32 + quad*8];
        #pragma unroll
        for (int j = 0; j < 2; j++)
            fb[j] = *(const bf16x8*)&sB[cur][(n0 + j*16 + fl)*32 + quad*8];
        #pragma unroll
        for (int i=0;i<4;i++)
        #pragma unroll
        for (int j=0;j<2;j++)
            acc[i][j] = __builtin_amdgcn_mfma_f32_16x16x32_bf16(fa[i], fb[j], acc[i][j], 0,0,0);
        __syncthreads();
    }
    #pragma unroll
    for (int i=0;i<4;i++)
    #pragma unroll
    for (int j=0;j<2;j++) {
        const int col = col0 + n0 + j*16 + fl;
        const float bb = bias ? bias[col] : 0.f;
        #pragma unroll
        for (int r=0;r<4;r++) {
            const int row = row0 + m0 + i*16 + quad*4 + r;
            float v = acc[i][j][r] + bb;
            if (RELU_OUT) v = fmaxf(v, 0.f);
            Cb[(size_t)row*512 + col] = (short)f2b(v);
        }
    }
}

// ======== x3 decoder GEMM: 128x64 tile, global_load_lds, 2-phase dbuf (round-6 verified) ========
// OUT_MODE: 0=fp32; 1=split bf16; 2=fp32 + split(relu(v))
template<int OUT_MODE, int RELU_OUT, int HAS_ADD>
__global__ __launch_bounds__(256) void gemm3b(
    const short* __restrict__ Ah, const short* __restrict__ Al,
    const short* __restrict__ Wh, const short* __restrict__ Wl,
    const float* __restrict__ bias, const float* __restrict__ addend,
    float* __restrict__ Cf, short* __restrict__ Ch, short* __restrict__ Cl)
{
    __shared__ short sAh[2][128*32], sAl[2][128*32], sBh[2][64*32], sBl[2][64*32]; // 48 KB
    const int t = threadIdx.x;
    const int nwg = gridDim.x * gridDim.y;
    const int flat = blockIdx.y * gridDim.x + blockIdx.x;
    const int per = nwg >> 3;
    const int sw = ((nwg & 7) == 0) ? ((flat & 7) * per + (flat >> 3)) : flat;
    const int bx = sw % gridDim.x, by = sw / gridDim.x;
    const int row0 = by * 128, col0 = bx * 64;
    const int lane = t & 63, w = t >> 6;
    const int m0 = (w >> 1) * 64, n0 = (w & 1) * 32;
    const int fl = lane & 15, quad = lane >> 4;

    f32x4 zero = {0.f,0.f,0.f,0.f};
    f32x4 acc[4][2];
    #pragma unroll
    for (int i=0;i<4;i++)
    #pragma unroll
    for (int j=0;j<2;j++) acc[i][j] = zero;

    auto stage = [&](int buf, int k0) {
        #pragma unroll
        for (int rnd = 0; rnd < 2; ++rnd) {
            const int idx = rnd*256 + t;
            const int r = idx >> 2, kp = (idx & 3) * 8;
            const int ldso = (rnd*256 + (t & 192)) * 8;
            const size_t ga = (size_t)(row0 + r)*512 + k0 + kp;
            gld_lds16(Ah + ga, &sAh[buf][ldso]);
            gld_lds16(Al + ga, &sAl[buf][ldso]);
        }
        {
            const int r = t >> 2, kp = (t & 3) * 8;
            const int ldso = (t & 192) * 8;
            const size_t gb = (size_t)(col0 + r)*512 + k0 + kp;
            gld_lds16(Wh + gb, &sBh[buf][ldso]);
            gld_lds16(Wl + gb, &sBl[buf][ldso]);
        }
    };

    stage(0, 0);
    __syncthreads();
    for (int k0 = 0; k0 < 512; k0 += 32) {
        const int cur = (k0 >> 5) & 1;
        if (k0 + 32 < 512) stage(cur ^ 1, k0 + 32);
        bf16x8 fah[4], fal[4], fbh[2], fbl[2];
        #pragma unroll
        for (int i = 0; i < 4; i++) {
            fah[i] = *(const bf16x8*)&sAh[cur][(m0 + i*16 + fl)*32 + quad*8];
            fal[i] = *(const bf16x8*)&sAl[cur][(m0 + i*16 + fl)*32 + quad*8];
        }
        #pragma unroll
        for (int j = 0; j < 2; j++) {
            fbh[j] = *(const bf16x8*)&sBh[cur][(n0 + j*16 + fl)*32 + quad*8];
            fbl[j] = *(const bf16x8*)&sBl[cur][(n0 + j*16 + fl)*32 + quad*8];
        }
        #pragma unroll
        for (int i=0;i<4;i++)
        #pragma unroll
        for (int j=0;j<2;j++)
            acc[i][j] = __builtin_amdgcn_mfma_f32_16x16x32_bf16(fah[i], fbh[j], acc[i][j], 0,0,0);
        #pragma unroll
        for (int i=0;i<4;i++)
        #pragma unroll
        for (int j=0;j<2;j++)
            acc[i][j] = __builtin_amdgcn_mfma_f32_16x16x32_bf16(fah[i], fbl[j], acc[i][j], 0,0,0);
        #pragma unroll
        for (int i=0;i<4;i++)
        #pragma unroll
        for (int j=0;j<2;j++)
            acc[i][j] = __builtin_amdgcn_mfma_f32_16x16x32_bf16(fal[i], fbh[j], acc[i][j], 0,0,0);
        __syncthreads();
    }
    #pragma unroll
    for (int i=0;i<4;i++)
    #pragma unroll
    for (int j=0;j<2;j++) {
        const int col = col0 + n0 + j*16 + fl;
        const float bb = bias ? bias[col] : 0.f;
        #pragma unroll
        for (int r=0;r<4;r++) {
            const int row = row0 + m0 + i*16 + quad*4 + r;
            const size_t off = (size_t)row*512 + col;
            float v = acc[i][j][r] + bb;
            if (HAS_ADD) v += addend[off];
            if (OUT_MODE == 0) {
                if (RELU_OUT) v = fmaxf(v,0.f);
                Cf[off] = v;
            } else if (OUT_MODE == 1) {
                if (RELU_OUT) v = fmaxf(v,0.f);
                short h,l; split2(v,h,l); Ch[off]=h; Cl[off]=l;
            } else {
                Cf[off] = v;
                short h,l; split2(fmaxf(v,0.f),h,l); Ch[off]=h; Cl[off]=l;
            }
        }
    }
}

// ======================= softmax + aggregation =======================
__global__ __launch_bounds__(256) void softmax_agg(
    const short* __restrict__ attn_preb, const short* __restrict__ pos_bf,
    const short* __restrict__ av_bf, const float* __restrict__ vgv,
    const int* __restrict__ knn, short* __restrict__ lath, short* __restrict__ latl, int qbase)
{
    __shared__ int sk[8];
    const int q = blockIdx.x;
    const int gq = qbase + q;
    const int b = gq >> 12;
    const int t = threadIdx.x;
    if (t < 8) sk[t] = knn[(size_t)gq*8 + t];
    __syncthreads();
    for (int c = t; c < 512; c += 256) {
        float p[9];
        #pragma unroll
        for (int n=0;n<9;n++) p[n] = b2f((unsigned short)attn_preb[(size_t)(q*9+n)*512 + c]);
        float m = p[0];
        #pragma unroll
        for (int n=1;n<9;n++) m = fmaxf(m, p[n]);
        float e[9], s = 0.f;
        #pragma unroll
        for (int n=0;n<9;n++){ e[n] = expf(p[n]-m); s += e[n]; }
        const float inv = 1.0f / s;
        float acc = 0.f;
        #pragma unroll
        for (int n=0;n<8;n++) {
            float vv = b2f((unsigned short)av_bf[(size_t)(b*NA + sk[n])*512 + c])
                     + b2f((unsigned short)pos_bf[(size_t)(q*8+n)*512 + c]);
            acc = fmaf(e[n]*inv, vv, acc);
        }
        acc = fmaf(e[8]*inv, vgv[b*512 + c], acc);
        short h,l; split2(acc,h,l);
        lath[(size_t)gq*512 + c] = h; latl[(size_t)gq*512 + c] = l;
    }
}

// ======================= PE + first decoder layer =======================
__global__ __launch_bounds__(256) void pe_fc(
    const float* __restrict__ xyz_q, const float* __restrict__ fw, const float* __restrict__ fb,
    float* __restrict__ net)
{
    __shared__ float spe[16*60];
    const int t = threadIdx.x;
    const int q0 = blockIdx.x * 16;
    for (int i=t;i<960;i+=256) {
        int ql = i/60, j = i - ql*60;
        int l = j/6; int r6 = j - l*6; int s = r6/3; int d = r6 - s*3;
        float pv = xyz_q[(size_t)(q0+ql)*3 + d];
        float a = pv * (3.14159265358979323846f * (float)(1<<l));
        spe[ql*60+j] = (s==0) ? sinf(a) : cosf(a);
    }
    __syncthreads();
    float acc0[16], acc1[16];
    #pragma unroll
    for (int ql=0;ql<16;ql++){ acc0[ql]=0.f; acc1[ql]=0.f; }
    const int c0 = t, c1 = t + 256;
    for (int k=0;k<60;k++) {
        float w0 = fw[k*512 + c0];
        float w1 = fw[k*512 + c1];
        #pragma unroll
        for (int ql=0;ql<16;ql++) {
            float pv = spe[ql*60+k];
            acc0[ql] = fmaf(pv, w0, acc0[ql]);
            acc1[ql] = fmaf(pv, w1, acc1[ql]);
        }
    }
    const float b0v = fb[c0], b1v = fb[c1];
    #pragma unroll
    for (int ql=0;ql<16;ql++) {
        net[(size_t)(q0+ql)*512 + c0] = acc0[ql] + b0v;
        net[(size_t)(q0+ql)*512 + c1] = acc1[ql] + b1v;
    }
}

// ======================= launch =======================
extern "C" void kernel_launch(void* const* d_in, const int* in_sizes, int n_in,
                              void* d_out, int out_size, void* d_ws, size_t ws_size,
                              hipStream_t stream) {
    const float* xyz_q  = (const float*)d_in[0];
    const float* gf     = (const float*)d_in[1];
    const float* axyz   = (const float*)d_in[2];
    const float* afeat  = (const float*)d_in[3];
    const float* w_qs   = (const float*)d_in[4];
    const float* w_ks   = (const float*)d_in[5];
    const float* w_vs   = (const float*)d_in[6];
    const float* w_kg   = (const float*)d_in[7];
    const float* w_vg   = (const float*)d_in[8];
    const float* d1_w   = (const float*)d_in[9];
    const float* d1_b   = (const float*)d_in[10];
    const float* d2_w   = (const float*)d_in[11];
    const float* d2_b   = (const float*)d_in[12];
    const float* g1_w   = (const float*)d_in[13];
    const float* g1_b   = (const float*)d_in[14];
    const float* g2_w   = (const float*)d_in[15];
    const float* g2_b   = (const float*)d_in[16];
    const float* fc_p_w = (const float*)d_in[17];
    const float* fc_p_b = (const float*)d_in[18];
    const float* fc_c_w = (const float*)d_in[19];
    const float* fc_c_b = (const float*)d_in[20];
    const float* blk0_w = (const float*)d_in[21];
    const float* blk0_b = (const float*)d_in[22];
    const float* blk1_w = (const float*)d_in[23];
    const float* blk1_b = (const float*)d_in[24];
    float* out = (float*)d_out;

    const size_t MB = 1u<<20;
    char* base = (char*)d_ws;
    const bool big = (ws_size >= (size_t)96*MB);
    const int CHr = big ? 2048 : 1024;
    // ---- persistent (21 MB) ----
    float* q_attn = (float*)base;
    float* kgv    = q_attn + 1024;
    float* vgv    = kgv + 1024;
    int*   knn    = (int*)(base + 16*1024);
    short* wksb = (short*)(base + 1*MB);
    short* wvsb = wksb + 262144;
    short* wd2b = wvsb + 262144;
    short* wg1b = wd2b + 262144;
    short* wg2b = wg1b + 262144;
    short* dch = (short*)(base + 1*MB);         short* dcl = dch + 262144;
    short* d0h = dcl + 262144;                  short* d0l = d0h + 262144;
    short* d1h = d0l + 262144;                  short* d1l = d1h + 262144;
    short* lath = (short*)(base + 5*MB);
    short* latl = (short*)(base + 13*MB);
    // ---- transient T ----
    char* T = base + 21*MB;
    short* ak_bf = (short*)T;                                  // 4 MB
    short* av_bf = (short*)(T + 4*MB);                         // 4 MB
    short* posb  = (short*)(T + 8*MB);                         // CHr*8*512*2
    char*  ybp   = (char*)posb + (size_t)CHr*8*512*2;
    short* yb    = (short*)ybp;                                // CHr*9*512*2
    short* attn_preb = (short*)(ybp + (size_t)CHr*9*512*2);    // CHr*9*512*2
    short* af_bf = (short*)(T + 8*MB);                         // phase A overlay
    short* peA  = attn_preb;
    short* g1A  = attn_preb;
    short* nrh = (short*)T;            short* nrl = (short*)(T + 8*MB);
    short* hdh = (short*)(T + 16*MB);  short* hdl = (short*)(T + 24*MB);
    short* dwH = (short*)(base + 81*MB);
    short* dwL = dwH + (size_t)15*262144;
    if (!big && (size_t)(55*MB) > ws_size) return;

    proj_small<<<dim3(6), dim3(256), 0, stream>>>(gf, w_qs, w_kg, w_vg, q_attn, kgv, vgv);
    knn_kernel<<<dim3(1024), dim3(256), 0, stream>>>(xyz_q, axyz, knn);

    cvt_bf16<<<dim3(1024), dim3(256), 0, stream>>>(afeat, af_bf);
    prep_w5<<<dim3(640), dim3(256), 0, stream>>>(w_ks, w_vs, d2_w, g1_w, g2_w,
                                                 wksb, wvsb, wd2b, wg1b, wg2b);
    if (big) {
        // hoisted: input-only, writes untouched region; off the decoder critical path
        prep_w3all<<<dim3(1920), dim3(256), 0, stream>>>(fc_c_w, blk0_w, blk1_w, dwH, dwL);
    }
    gemm1b<0><<<dim3(8, 32), dim3(256), 0, stream>>>(af_bf, wksb, nullptr, ak_bf);
    gemm1b<0><<<dim3(8, 32), dim3(256), 0, stream>>>(af_bf, wvsb, nullptr, av_bf);

    for (int qbase = 0; qbase < B*NQ; qbase += CHr) {
        pe_make<<<dim3(CHr*8/4), dim3(256), 0, stream>>>(xyz_q, axyz, knn, d1_w, d1_b, peA, qbase);
        gemm1b<0><<<dim3(8, CHr*8/128), dim3(256), 0, stream>>>(peA, wd2b, d2_b, posb);
        g1_make<<<dim3(CHr*9/4), dim3(256), 0, stream>>>(q_attn, kgv, ak_bf, posb, knn, g1A, qbase);
        gemm1b<1><<<dim3(8, CHr*9/128), dim3(256), 0, stream>>>(g1A, wg1b, g1_b, yb);
        gemm1b<0><<<dim3(8, CHr*9/128), dim3(256), 0, stream>>>(yb, wg2b, g2_b, attn_preb);
        softmax_agg<<<dim3(CHr), dim3(256), 0, stream>>>(attn_preb, posb, av_bf, vgv, knn, lath, latl, qbase);
    }

    pe_fc<<<dim3(512), dim3(256), 0, stream>>>(xyz_q, fc_p_w, fc_p_b, out);
    if (big) {
        for (int i=0;i<5;i++) {
            const float* cb  = fc_c_b + (size_t)i*512;
            const float* b0b = blk0_b + (size_t)i*512;
            const float* b1b = blk1_b + (size_t)i*512;
            short* ch = dwH + (size_t)(i*3+0)*262144; short* cl = dwL + (size_t)(i*3+0)*262144;
            short* h0 = dwH + (size_t)(i*3+1)*262144; short* l0 = dwL + (size_t)(i*3+1)*262144;
            short* h1 = dwH + (size_t)(i*3+2)*262144; short* l1 = dwL + (size_t)(i*3+2)*262144;
            gemm3b<2,0,1><<<dim3(8,64), dim3(256), 0, stream>>>(lath, latl, ch, cl, cb, out, out, nrh, nrl);
            gemm3b<1,1,0><<<dim3(8,64), dim3(256), 0, stream>>>(nrh, nrl, h0, l0, b0b, nullptr, nullptr, hdh, hdl);
            gemm3b<0,0,1><<<dim3(8,64), dim3(256), 0, stream>>>(hdh, hdl, h1, l1, b1b, out, out, nullptr, nullptr);
        }
    } else {
        for (int i=0;i<5;i++) {
            const float* cw  = fc_c_w + (size_t)i*512*512;
            const float* cb  = fc_c_b + (size_t)i*512;
            const float* b0w = blk0_w + (size_t)i*512*512;
            const float* b0b = blk0_b + (size_t)i*512;
            const float* b1w = blk1_w + (size_t)i*512*512;
            const float* b1b = blk1_b + (size_t)i*512;
            prep_w3<<<dim3(384), dim3(256), 0, stream>>>(cw, b0w, b1w, dch, dcl, d0h, d0l, d1h, d1l);
            gemm3b<2,0,1><<<dim3(8,64), dim3(256), 0, stream>>>(lath, latl, dch, dcl, cb, out, out, nrh, nrl);
            gemm3b<1,1,0><<<dim3(8,64), dim3(256), 0, stream>>>(nrh, nrl, d0h, d0l, b0b, nullptr, nullptr, hdh, hdl);
            gemm3b<0,0,1><<<dim3(8,64), dim3(256), 0, stream>>>(hdh, hdl, d1h, d1l, b1b, out, out, nullptr, nullptr);
        }
    }
}

// Round 11
// 974.970 us; speedup vs baseline: 1.0623x; 1.0019x over previous
//
#include <hip/hip_runtime.h>

#define B 2
#define NQ 4096
#define NA 2048

typedef __attribute__((ext_vector_type(8))) short bf16x8;
typedef __attribute__((ext_vector_type(4))) float f32x4;

__device__ __forceinline__ float b2f(unsigned short u){ union{unsigned i; float f;} c; c.i=((unsigned)u)<<16; return c.f; }
__device__ __forceinline__ unsigned short f2b(float f){ union{float f; unsigned u;} c; c.f=f; unsigned u=c.u; u += 0x7FFFu + ((u>>16)&1u); return (unsigned short)(u>>16); }
__device__ __forceinline__ void split2(float x, short& h, short& l){
    unsigned short hh = f2b(x); h = (short)hh; l = (short)f2b(x - b2f(hh));
}
__device__ __forceinline__ float4 ld4(const float* p){ return *(const float4*)p; }

// async global->LDS, 16B per lane; LDS dest is wave-uniform base (+lane*16 by HW)
__device__ __forceinline__ void gld_lds16(const void* g, void* s) {
    __builtin_amdgcn_global_load_lds(
        (__attribute__((address_space(1))) unsigned int*)g,
        (__attribute__((address_space(3))) unsigned int*)s,
        16, 0, 0);
}

// ======================= small projections =======================
__global__ __launch_bounds__(256) void proj_small(
    const float* __restrict__ gf,
    const float* __restrict__ w_qs, const float* __restrict__ w_kg, const float* __restrict__ w_vg,
    float* __restrict__ q_attn, float* __restrict__ kgv, float* __restrict__ vgv)
{
    int mat = blockIdx.x >> 1, b = blockIdx.x & 1;
    const float* W = (mat==0) ? w_qs : (mat==1 ? w_kg : w_vg);
    float* O       = (mat==0) ? q_attn : (mat==1 ? kgv : vgv);
    __shared__ float sg[512];
    int t = threadIdx.x;
    for (int i=t;i<512;i+=256) sg[i] = gf[b*512+i];
    __syncthreads();
    for (int c=t;c<512;c+=256) {
        float acc = 0.f;
        for (int k=0;k<512;k++) acc = fmaf(sg[k], W[k*512+c], acc);
        O[b*512+c] = acc;
    }
}

// ============ KNN: f64 distances (load-bearing for neighbor ordering), 8q x 32 lanes,
// register-resident shfl_xor bitonic tree merge (verified 52-54 us) ============
__global__ __launch_bounds__(256) void knn_kernel(
    const float* __restrict__ xyz_q, const float* __restrict__ axyz, int* __restrict__ knn)
{
    __shared__ float sax[NA], say[NA], saz[NA];   // 24 KB only
    const int t = threadIdx.x;
    const int b  = blockIdx.x >> 9;
    const int qi = t >> 5;
    const int q  = ((blockIdx.x & 511) << 3) + qi;
    const int g  = t & 31;
    for (int i=t;i<NA;i+=256) {
        const float* ap = axyz + (size_t)(b*NA+i)*3;
        sax[i]=ap[0]; say[i]=ap[1]; saz[i]=ap[2];
    }
    __syncthreads();
    const double qx = (double)xyz_q[(size_t)(b*NQ+q)*3+0];
    const double qy = (double)xyz_q[(size_t)(b*NQ+q)*3+1];
    const double qz = (double)xyz_q[(size_t)(b*NQ+q)*3+2];
    const double qq = (qx*qx + qy*qy) + qz*qz;
    double best[8]; int bid[8];
    #pragma unroll
    for (int j=0;j<8;j++){ best[j]=1.0e300; bid[j]=0; }
    for (int jj=0; jj<64; jj++) {
        const int i = jj*32 + g;
        double ax=(double)sax[i], ay=(double)say[i], az=(double)saz[i];
        double aa  = (ax*ax + ay*ay) + az*az;
        double dot = (qx*ax + qy*ay) + qz*az;
        double dd  = (qq + aa) - 2.0*dot;
        if (dd < best[7]) {
            best[7]=dd; bid[7]=i;
            #pragma unroll
            for (int j=7;j>0;--j) if (best[j] < best[j-1]) {
                double tf=best[j]; best[j]=best[j-1]; best[j-1]=tf;
                int ti=bid[j]; bid[j]=bid[j-1]; bid[j-1]=ti;
            }
        }
    }
    // 5-stage tree merge across the 32 lanes of this query, fully in registers.
    #pragma unroll
    for (int s=16; s>=1; s>>=1) {
        double pb[8]; int pbi[8];
        #pragma unroll
        for (int j=0;j<8;j++){
            pb[j]  = __shfl_xor(best[j], s, 64);
            pbi[j] = __shfl_xor(bid[j],  s, 64);
        }
        #pragma unroll
        for (int i=0;i<8;i++) {
            double bo = pb[7-i]; int boi = pbi[7-i];
            if (bo < best[i]) { best[i]=bo; bid[i]=boi; }
        }
        #pragma unroll
        for (int i=0;i<4;i++) {
            if (best[i] > best[i+4]) {
                double td=best[i]; best[i]=best[i+4]; best[i+4]=td;
                int ti=bid[i]; bid[i]=bid[i+4]; bid[i+4]=ti;
            }
        }
        #pragma unroll
        for (int ii=0;ii<2;ii++)
        #pragma unroll
        for (int jj2=0;jj2<2;jj2++) {
            int i = ii*4 + jj2;
            if (best[i] > best[i+2]) {
                double td=best[i]; best[i]=best[i+2]; best[i+2]=td;
                int ti=bid[i]; bid[i]=bid[i+2]; bid[i+2]=ti;
            }
        }
        #pragma unroll
        for (int ii=0;ii<4;ii++) {
            int i = ii*2;
            if (best[i] > best[i+1]) {
                double td=best[i]; best[i]=best[i+1]; best[i+1]=td;
                int ti=bid[i]; bid[i]=bid[i+1]; bid[i+1]=ti;
            }
        }
    }
    if (g == 0) {
        #pragma unroll
        for (int j=0;j<8;j++) knn[(size_t)(b*NQ+q)*8+j] = bid[j];
    }
}

// ======================= weight prep =======================
__global__ __launch_bounds__(256) void prep_w5(
    const float* __restrict__ W0, const float* __restrict__ W1, const float* __restrict__ W2,
    const float* __restrict__ W3, const float* __restrict__ W4,
    short* __restrict__ O0, short* __restrict__ O1, short* __restrict__ O2,
    short* __restrict__ O3, short* __restrict__ O4)
{
    const int m = blockIdx.x >> 7;
    const float* W = (m==0)?W0:(m==1)?W1:(m==2)?W2:(m==3)?W3:W4;
    short* Wb      = (m==0)?O0:(m==1)?O1:(m==2)?O2:(m==3)?O3:O4;
    const int gid = (blockIdx.x & 127)*256 + threadIdx.x;
    const int n  = gid & 511;
    const int kc = (gid >> 9) * 8;
    short o[8];
    #pragma unroll
    for (int j=0;j<8;j++) o[j] = (short)f2b(W[(size_t)(kc+j)*512 + n]);
    *(short4*)&Wb[(size_t)n*512 + kc]     = make_short4(o[0],o[1],o[2],o[3]);
    *(short4*)&Wb[(size_t)n*512 + kc + 4] = make_short4(o[4],o[5],o[6],o[7]);
}
// per-layer prep (small-ws path)
__global__ __launch_bounds__(256) void prep_w3(
    const float* __restrict__ W0, const float* __restrict__ W1, const float* __restrict__ W2,
    short* __restrict__ H0, short* __restrict__ L0,
    short* __restrict__ H1, short* __restrict__ L1,
    short* __restrict__ H2, short* __restrict__ L2)
{
    const int m = blockIdx.x >> 7;
    const float* W = (m==0)?W0:(m==1)?W1:W2;
    short* Wh = (m==0)?H0:(m==1)?H1:H2;
    short* Wl = (m==0)?L0:(m==1)?L1:L2;
    const int gid = (blockIdx.x & 127)*256 + threadIdx.x;
    const int n  = gid & 511;
    const int kc = (gid >> 9) * 8;
    short hi[8], lo[8];
    #pragma unroll
    for (int j=0;j<8;j++) split2(W[(size_t)(kc+j)*512 + n], hi[j], lo[j]);
    *(short4*)&Wh[(size_t)n*512 + kc]     = make_short4(hi[0],hi[1],hi[2],hi[3]);
    *(short4*)&Wh[(size_t)n*512 + kc + 4] = make_short4(hi[4],hi[5],hi[6],hi[7]);
    *(short4*)&Wl[(size_t)n*512 + kc]     = make_short4(lo[0],lo[1],lo[2],lo[3]);
    *(short4*)&Wl[(size_t)n*512 + kc + 4] = make_short4(lo[4],lo[5],lo[6],lo[7]);
}
// all-15-matrices prep (big-ws path)
__global__ __launch_bounds__(256) void prep_w3all(
    const float* __restrict__ CW, const float* __restrict__ B0W, const float* __restrict__ B1W,
    short* __restrict__ DH, short* __restrict__ DL)
{
    const int m = blockIdx.x >> 7;           // 0..14
    const int layer = m / 3, which = m - layer*3;
    const float* W = (which==0 ? CW : which==1 ? B0W : B1W) + (size_t)layer*262144;
    short* Wh = DH + (size_t)m*262144;
    short* Wl = DL + (size_t)m*262144;
    const int gid = (blockIdx.x & 127)*256 + threadIdx.x;
    const int n  = gid & 511;
    const int kc = (gid >> 9) * 8;
    short hi[8], lo[8];
    #pragma unroll
    for (int j=0;j<8;j++) split2(W[(size_t)(kc+j)*512 + n], hi[j], lo[j]);
    *(short4*)&Wh[(size_t)n*512 + kc]     = make_short4(hi[0],hi[1],hi[2],hi[3]);
    *(short4*)&Wh[(size_t)n*512 + kc + 4] = make_short4(hi[4],hi[5],hi[6],hi[7]);
    *(short4*)&Wl[(size_t)n*512 + kc]     = make_short4(lo[0],lo[1],lo[2],lo[3]);
    *(short4*)&Wl[(size_t)n*512 + kc + 4] = make_short4(lo[4],lo[5],lo[6],lo[7]);
}

// ======================= fp32 -> single bf16 =======================
__global__ __launch_bounds__(256) void cvt_bf16(
    const float* __restrict__ X, short* __restrict__ Xb)
{
    const size_t i0 = ((size_t)blockIdx.x*256 + threadIdx.x)*8;
    float4 a = *(const float4*)(X+i0), bq = *(const float4*)(X+i0+4);
    float v[8] = {a.x,a.y,a.z,a.w,bq.x,bq.y,bq.z,bq.w};
    short o[8];
    #pragma unroll
    for (int j=0;j<8;j++) o[j] = (short)f2b(v[j]);
    *(short4*)(Xb+i0)   = make_short4(o[0],o[1],o[2],o[3]);
    *(short4*)(Xb+i0+4) = make_short4(o[4],o[5],o[6],o[7]);
}

// ======== A-materialization: pos-encoder A = relu(d@d1w+d1b), bf16 ========
__global__ __launch_bounds__(256) void pe_make(
    const float* __restrict__ xyz_q, const float* __restrict__ axyz, const int* __restrict__ knn,
    const float* __restrict__ d1w, const float* __restrict__ d1b,
    short* __restrict__ peA, int qbase)
{
    const int t = threadIdx.x;
    const int r  = blockIdx.x*4 + (t >> 6);
    const int col0 = (t & 63) * 8;
    const int gr = qbase*8 + r;
    const int b  = gr >> 15;
    const int gq = gr >> 3;
    const int idx = knn[gr];
    const float* qp = xyz_q + (size_t)gq*3;
    const float* ap = axyz + (size_t)(b*NA + idx)*3;
    const float dx = qp[0]-ap[0], dy = qp[1]-ap[1], dz = qp[2]-ap[2];
    short o[8];
    #pragma unroll
    for (int j=0;j<8;j++) {
        const int k = col0 + j;
        float v = fmaf(dx, d1w[k], fmaf(dy, d1w[512+k], fmaf(dz, d1w[1024+k], d1b[k])));
        o[j] = (short)f2b(fmaxf(v, 0.f));
    }
    *(short4*)&peA[(size_t)r*512 + col0]     = make_short4(o[0],o[1],o[2],o[3]);
    *(short4*)&peA[(size_t)r*512 + col0 + 4] = make_short4(o[4],o[5],o[6],o[7]);
}

// ======== A-materialization: g1 A = q_attn - k + pos, bf16 ========
__global__ __launch_bounds__(256) void g1_make(
    const float* __restrict__ q_attn, const float* __restrict__ kgv,
    const short* __restrict__ ak_bf, const short* __restrict__ pos_bf, const int* __restrict__ knn,
    short* __restrict__ g1A, int qbase)
{
    const int t = threadIdx.x;
    const int r = blockIdx.x*4 + (t >> 6);
    const int col0 = (t & 63) * 8;
    const int b = qbase >> 12;
    const int q = r / 9, n = r - q*9;
    float4 qa0 = ld4(q_attn + b*512 + col0);
    float4 qa1 = ld4(q_attn + b*512 + col0 + 4);
    short o[8];
    if (n < 8) {
        const int ao = b*NA + knn[(size_t)(qbase + q)*8 + n];
        const int po = q*8 + n;
        ushort4 kv0 = *(const ushort4*)(ak_bf + (size_t)ao*512 + col0);
        ushort4 kv1 = *(const ushort4*)(ak_bf + (size_t)ao*512 + col0 + 4);
        ushort4 pv0 = *(const ushort4*)(pos_bf + (size_t)po*512 + col0);
        ushort4 pv1 = *(const ushort4*)(pos_bf + (size_t)po*512 + col0 + 4);
        o[0]=(short)f2b(qa0.x - b2f(kv0.x) + b2f(pv0.x));
        o[1]=(short)f2b(qa0.y - b2f(kv0.y) + b2f(pv0.y));
        o[2]=(short)f2b(qa0.z - b2f(kv0.z) + b2f(pv0.z));
        o[3]=(short)f2b(qa0.w - b2f(kv0.w) + b2f(pv0.w));
        o[4]=(short)f2b(qa1.x - b2f(kv1.x) + b2f(pv1.x));
        o[5]=(short)f2b(qa1.y - b2f(kv1.y) + b2f(pv1.y));
        o[6]=(short)f2b(qa1.z - b2f(kv1.z) + b2f(pv1.z));
        o[7]=(short)f2b(qa1.w - b2f(kv1.w) + b2f(pv1.w));
    } else {
        float4 gk0 = ld4(kgv + b*512 + col0);
        float4 gk1 = ld4(kgv + b*512 + col0 + 4);
        o[0]=(short)f2b(qa0.x - gk0.x); o[1]=(short)f2b(qa0.y - gk0.y);
        o[2]=(short)f2b(qa0.z - gk0.z); o[3]=(short)f2b(qa0.w - gk0.w);
        o[4]=(short)f2b(qa1.x - gk1.x); o[5]=(short)f2b(qa1.y - gk1.y);
        o[6]=(short)f2b(qa1.z - gk1.z); o[7]=(short)f2b(qa1.w - gk1.w);
    }
    *(short4*)&g1A[(size_t)r*512 + col0]     = make_short4(o[0],o[1],o[2],o[3]);
    *(short4*)&g1A[(size_t)r*512 + col0 + 4] = make_short4(o[4],o[5],o[6],o[7]);
}

// ======== x1 GEMM: 128x64 tile, global_load_lds, 2-phase dbuf (round-6 verified) ========
template<int RELU_OUT>
__global__ __launch_bounds__(256) void gemm1b(
    const short* __restrict__ Ab, const short* __restrict__ Wb,
    const float* __restrict__ bias, short* __restrict__ Cb)
{
    __shared__ short sA[2][128*32], sB[2][64*32];   // 24KB
    const int t = threadIdx.x;
    const int nwg = gridDim.x * gridDim.y;
    const int flat = blockIdx.y * gridDim.x + blockIdx.x;
    const int per = nwg >> 3;
    const int sw = ((nwg & 7) == 0) ? ((flat & 7) * per + (flat >> 3)) : flat;
    const int bx = sw % gridDim.x, by = sw / gridDim.x;
    const int row0 = by * 128, col0 = bx * 64;
    const int lane = t & 63, w = t >> 6;
    const int m0 = (w >> 1) * 64, n0 = (w & 1) * 32;
    const int fl = lane & 15, quad = lane >> 4;

    f32x4 zero = {0.f,0.f,0.f,0.f};
    f32x4 acc[4][2];
    #pragma unroll
    for (int i=0;i<4;i++)
    #pragma unroll
    for (int j=0;j<2;j++) acc[i][j] = zero;

    auto stage = [&](int buf, int k0) {
        #pragma unroll
        for (int rnd = 0; rnd < 2; ++rnd) {
            const int idx = rnd*256 + t;
            const int r = idx >> 2, kp = (idx & 3) * 8;
            const int ldso = (rnd*256 + (t & 192)) * 8;
            gld_lds16(Ab + (size_t)(row0 + r)*512 + k0 + kp, &sA[buf][ldso]);
        }
        {
            const int r = t >> 2, kp = (t & 3) * 8;
            const int ldso = (t & 192) * 8;
            gld_lds16(Wb + (size_t)(col0 + r)*512 + k0 + kp, &sB[buf][ldso]);
        }
    };

    stage(0, 0);
    __syncthreads();
    for (int k0 = 0; k0 < 512; k0 += 32) {
        const int cur = (k0 >> 5) & 1;
        if (k0 + 32 < 512) stage(cur ^ 1, k0 + 32);
        bf16x8 fa[4], fb[2];
        #pragma unroll
        for (int i = 0; i < 4; i++)
            fa[i] = *(const bf16x8*)&sA[cur][(m0 + i*16 + fl)*32 + quad*8];
        #pragma unroll
        for (int j = 0; j < 2; j++)
            fb[j] = *(const bf16x8*)&sB[cur][(n0 + j*16 + fl)*32 + quad*8];
        #pragma unroll
        for (int i=0;i<4;i++)
        #pragma unroll
        for (int j=0;j<2;j++)
            acc[i][j] = __builtin_amdgcn_mfma_f32_16x16x32_bf16(fa[i], fb[j], acc[i][j], 0,0,0);
        __syncthreads();
    }
    #pragma unroll
    for (int i=0;i<4;i++)
    #pragma unroll
    for (int j=0;j<2;j++) {
        const int col = col0 + n0 + j*16 + fl;
        const float bb = bias ? bias[col] : 0.f;
        #pragma unroll
        for (int r=0;r<4;r++) {
            const int row = row0 + m0 + i*16 + quad*4 + r;
            float v = acc[i][j][r] + bb;
            if (RELU_OUT) v = fmaxf(v, 0.f);
            Cb[(size_t)row*512 + col] = (short)f2b(v);
        }
    }
}

// ======== x1 GEMM m97-shape: 128x128 block, 4 waves x 64x64, 32KB LDS ========
// Used ONLY for the big-path loop GEMMs where grid >= 512 blocks (>=2 blocks/CU).
template<int RELU_OUT>
__global__ __launch_bounds__(256) void gemm1c(
    const short* __restrict__ Ab, const short* __restrict__ Wb,
    const float* __restrict__ bias, short* __restrict__ Cb)
{
    __shared__ short sA[2][128*32], sB[2][128*32];   // 32KB
    const int t = threadIdx.x;
    const int nwg = gridDim.x * gridDim.y;
    const int flat = blockIdx.y * gridDim.x + blockIdx.x;
    const int per = nwg >> 3;
    const int sw = ((nwg & 7) == 0) ? ((flat & 7) * per + (flat >> 3)) : flat;
    const int bx = sw % gridDim.x, by = sw / gridDim.x;
    const int row0 = by * 128, col0 = bx * 128;
    const int lane = t & 63, w = t >> 6;
    const int m0 = (w >> 1) * 64, n0 = (w & 1) * 64;
    const int fl = lane & 15, quad = lane >> 4;

    f32x4 zero = {0.f,0.f,0.f,0.f};
    f32x4 acc[4][4];
    #pragma unroll
    for (int i=0;i<4;i++)
    #pragma unroll
    for (int j=0;j<4;j++) acc[i][j] = zero;

    auto stage = [&](int buf, int k0) {
        #pragma unroll
        for (int rnd = 0; rnd < 2; ++rnd) {
            const int idx = rnd*256 + t;
            const int r = idx >> 2, kp = (idx & 3) * 8;
            const int ldso = (rnd*256 + (t & 192)) * 8;
            gld_lds16(Ab + (size_t)(row0 + r)*512 + k0 + kp, &sA[buf][ldso]);
            gld_lds16(Wb + (size_t)(col0 + r)*512 + k0 + kp, &sB[buf][ldso]);
        }
    };

    stage(0, 0);
    __syncthreads();
    for (int k0 = 0; k0 < 512; k0 += 32) {
        const int cur = (k0 >> 5) & 1;
        if (k0 + 32 < 512) stage(cur ^ 1, k0 + 32);
        bf16x8 fa[4], fb[4];
        #pragma unroll
        for (int i = 0; i < 4; i++) {
            fa[i] = *(const bf16x8*)&sA[cur][(m0 + i*16 + fl)*32 + quad*8];
            fb[i] = *(const bf16x8*)&sB[cur][(n0 + i*16 + fl)*32 + quad*8];
        }
        #pragma unroll
        for (int i=0;i<4;i++)
        #pragma unroll
        for (int j=0;j<4;j++)
            acc[i][j] = __builtin_amdgcn_mfma_f32_16x16x32_bf16(fa[i], fb[j], acc[i][j], 0,0,0);
        __syncthreads();
    }
    #pragma unroll
    for (int i=0;i<4;i++)
    #pragma unroll
    for (int j=0;j<4;j++) {
        const int col = col0 + n0 + j*16 + fl;
        const float bb = bias ? bias[col] : 0.f;
        #pragma unroll
        for (int r=0;r<4;r++) {
            const int row = row0 + m0 + i*16 + quad*4 + r;
            float v = acc[i][j][r] + bb;
            if (RELU_OUT) v = fmaxf(v, 0.f);
            Cb[(size_t)row*512 + col] = (short)f2b(v);
        }
    }
}

// ======== x3 decoder GEMM: 128x64 tile, global_load_lds, 2-phase dbuf (round-6 verified) ========
// OUT_MODE: 0=fp32; 1=split bf16; 2=fp32 + split(relu(v))
template<int OUT_MODE, int RELU_OUT, int HAS_ADD>
__global__ __launch_bounds__(256) void gemm3b(
    const short* __restrict__ Ah, const short* __restrict__ Al,
    const short* __restrict__ Wh, const short* __restrict__ Wl,
    const float* __restrict__ bias, const float* __restrict__ addend,
    float* __restrict__ Cf, short* __restrict__ Ch, short* __restrict__ Cl)
{
    __shared__ short sAh[2][128*32], sAl[2][128*32], sBh[2][64*32], sBl[2][64*32]; // 48 KB
    const int t = threadIdx.x;
    const int nwg = gridDim.x * gridDim.y;
    const int flat = blockIdx.y * gridDim.x + blockIdx.x;
    const int per = nwg >> 3;
    const int sw = ((nwg & 7) == 0) ? ((flat & 7) * per + (flat >> 3)) : flat;
    const int bx = sw % gridDim.x, by = sw / gridDim.x;
    const int row0 = by * 128, col0 = bx * 64;
    const int lane = t & 63, w = t >> 6;
    const int m0 = (w >> 1) * 64, n0 = (w & 1) * 32;
    const int fl = lane & 15, quad = lane >> 4;

    f32x4 zero = {0.f,0.f,0.f,0.f};
    f32x4 acc[4][2];
    #pragma unroll
    for (int i=0;i<4;i++)
    #pragma unroll
    for (int j=0;j<2;j++) acc[i][j] = zero;

    auto stage = [&](int buf, int k0) {
        #pragma unroll
        for (int rnd = 0; rnd < 2; ++rnd) {
            const int idx = rnd*256 + t;
            const int r = idx >> 2, kp = (idx & 3) * 8;
            const int ldso = (rnd*256 + (t & 192)) * 8;
            const size_t ga = (size_t)(row0 + r)*512 + k0 + kp;
            gld_lds16(Ah + ga, &sAh[buf][ldso]);
            gld_lds16(Al + ga, &sAl[buf][ldso]);
        }
        {
            const int r = t >> 2, kp = (t & 3) * 8;
            const int ldso = (t & 192) * 8;
            const size_t gb = (size_t)(col0 + r)*512 + k0 + kp;
            gld_lds16(Wh + gb, &sBh[buf][ldso]);
            gld_lds16(Wl + gb, &sBl[buf][ldso]);
        }
    };

    stage(0, 0);
    __syncthreads();
    for (int k0 = 0; k0 < 512; k0 += 32) {
        const int cur = (k0 >> 5) & 1;
        if (k0 + 32 < 512) stage(cur ^ 1, k0 + 32);
        bf16x8 fah[4], fal[4], fbh[2], fbl[2];
        #pragma unroll
        for (int i = 0; i < 4; i++) {
            fah[i] = *(const bf16x8*)&sAh[cur][(m0 + i*16 + fl)*32 + quad*8];
            fal[i] = *(const bf16x8*)&sAl[cur][(m0 + i*16 + fl)*32 + quad*8];
        }
        #pragma unroll
        for (int j = 0; j < 2; j++) {
            fbh[j] = *(const bf16x8*)&sBh[cur][(n0 + j*16 + fl)*32 + quad*8];
            fbl[j] = *(const bf16x8*)&sBl[cur][(n0 + j*16 + fl)*32 + quad*8];
        }
        #pragma unroll
        for (int i=0;i<4;i++)
        #pragma unroll
        for (int j=0;j<2;j++)
            acc[i][j] = __builtin_amdgcn_mfma_f32_16x16x32_bf16(fah[i], fbh[j], acc[i][j], 0,0,0);
        #pragma unroll
        for (int i=0;i<4;i++)
        #pragma unroll
        for (int j=0;j<2;j++)
            acc[i][j] = __builtin_amdgcn_mfma_f32_16x16x32_bf16(fah[i], fbl[j], acc[i][j], 0,0,0);
        #pragma unroll
        for (int i=0;i<4;i++)
        #pragma unroll
        for (int j=0;j<2;j++)
            acc[i][j] = __builtin_amdgcn_mfma_f32_16x16x32_bf16(fal[i], fbh[j], acc[i][j], 0,0,0);
        __syncthreads();
    }
    #pragma unroll
    for (int i=0;i<4;i++)
    #pragma unroll
    for (int j=0;j<2;j++) {
        const int col = col0 + n0 + j*16 + fl;
        const float bb = bias ? bias[col] : 0.f;
        #pragma unroll
        for (int r=0;r<4;r++) {
            const int row = row0 + m0 + i*16 + quad*4 + r;
            const size_t off = (size_t)row*512 + col;
            float v = acc[i][j][r] + bb;
            if (HAS_ADD) v += addend[off];
            if (OUT_MODE == 0) {
                if (RELU_OUT) v = fmaxf(v,0.f);
                Cf[off] = v;
            } else if (OUT_MODE == 1) {
                if (RELU_OUT) v = fmaxf(v,0.f);
                short h,l; split2(v,h,l); Ch[off]=h; Cl[off]=l;
            } else {
                Cf[off] = v;
                short h,l; split2(fmaxf(v,0.f),h,l); Ch[off]=h; Cl[off]=l;
            }
        }
    }
}

// ======================= softmax + aggregation =======================
__global__ __launch_bounds__(256) void softmax_agg(
    const short* __restrict__ attn_preb, const short* __restrict__ pos_bf,
    const short* __restrict__ av_bf, const float* __restrict__ vgv,
    const int* __restrict__ knn, short* __restrict__ lath, short* __restrict__ latl, int qbase)
{
    __shared__ int sk[8];
    const int q = blockIdx.x;
    const int gq = qbase + q;
    const int b = gq >> 12;
    const int t = threadIdx.x;
    if (t < 8) sk[t] = knn[(size_t)gq*8 + t];
    __syncthreads();
    for (int c = t; c < 512; c += 256) {
        float p[9];
        #pragma unroll
        for (int n=0;n<9;n++) p[n] = b2f((unsigned short)attn_preb[(size_t)(q*9+n)*512 + c]);
        float m = p[0];
        #pragma unroll
        for (int n=1;n<9;n++) m = fmaxf(m, p[n]);
        float e[9], s = 0.f;
        #pragma unroll
        for (int n=0;n<9;n++){ e[n] = expf(p[n]-m); s += e[n]; }
        const float inv = 1.0f / s;
        float acc = 0.f;
        #pragma unroll
        for (int n=0;n<8;n++) {
            float vv = b2f((unsigned short)av_bf[(size_t)(b*NA + sk[n])*512 + c])
                     + b2f((unsigned short)pos_bf[(size_t)(q*8+n)*512 + c]);
            acc = fmaf(e[n]*inv, vv, acc);
        }
        acc = fmaf(e[8]*inv, vgv[b*512 + c], acc);
        short h,l; split2(acc,h,l);
        lath[(size_t)gq*512 + c] = h; latl[(size_t)gq*512 + c] = l;
    }
}

// ======================= PE + first decoder layer =======================
__global__ __launch_bounds__(256) void pe_fc(
    const float* __restrict__ xyz_q, const float* __restrict__ fw, const float* __restrict__ fb,
    float* __restrict__ net)
{
    __shared__ float spe[16*60];
    const int t = threadIdx.x;
    const int q0 = blockIdx.x * 16;
    for (int i=t;i<960;i+=256) {
        int ql = i/60, j = i - ql*60;
        int l = j/6; int r6 = j - l*6; int s = r6/3; int d = r6 - s*3;
        float pv = xyz_q[(size_t)(q0+ql)*3 + d];
        float a = pv * (3.14159265358979323846f * (float)(1<<l));
        spe[ql*60+j] = (s==0) ? sinf(a) : cosf(a);
    }
    __syncthreads();
    float acc0[16], acc1[16];
    #pragma unroll
    for (int ql=0;ql<16;ql++){ acc0[ql]=0.f; acc1[ql]=0.f; }
    const int c0 = t, c1 = t + 256;
    for (int k=0;k<60;k++) {
        float w0 = fw[k*512 + c0];
        float w1 = fw[k*512 + c1];
        #pragma unroll
        for (int ql=0;ql<16;ql++) {
            float pv = spe[ql*60+k];
            acc0[ql] = fmaf(pv, w0, acc0[ql]);
            acc1[ql] = fmaf(pv, w1, acc1[ql]);
        }
    }
    const float b0v = fb[c0], b1v = fb[c1];
    #pragma unroll
    for (int ql=0;ql<16;ql++) {
        net[(size_t)(q0+ql)*512 + c0] = acc0[ql] + b0v;
        net[(size_t)(q0+ql)*512 + c1] = acc1[ql] + b1v;
    }
}

// ======================= launch =======================
extern "C" void kernel_launch(void* const* d_in, const int* in_sizes, int n_in,
                              void* d_out, int out_size, void* d_ws, size_t ws_size,
                              hipStream_t stream) {
    const float* xyz_q  = (const float*)d_in[0];
    const float* gf     = (const float*)d_in[1];
    const float* axyz   = (const float*)d_in[2];
    const float* afeat  = (const float*)d_in[3];
    const float* w_qs   = (const float*)d_in[4];
    const float* w_ks   = (const float*)d_in[5];
    const float* w_vs   = (const float*)d_in[6];
    const float* w_kg   = (const float*)d_in[7];
    const float* w_vg   = (const float*)d_in[8];
    const float* d1_w   = (const float*)d_in[9];
    const float* d1_b   = (const float*)d_in[10];
    const float* d2_w   = (const float*)d_in[11];
    const float* d2_b   = (const float*)d_in[12];
    const float* g1_w   = (const float*)d_in[13];
    const float* g1_b   = (const float*)d_in[14];
    const float* g2_w   = (const float*)d_in[15];
    const float* g2_b   = (const float*)d_in[16];
    const float* fc_p_w = (const float*)d_in[17];
    const float* fc_p_b = (const float*)d_in[18];
    const float* fc_c_w = (const float*)d_in[19];
    const float* fc_c_b = (const float*)d_in[20];
    const float* blk0_w = (const float*)d_in[21];
    const float* blk0_b = (const float*)d_in[22];
    const float* blk1_w = (const float*)d_in[23];
    const float* blk1_b = (const float*)d_in[24];
    float* out = (float*)d_out;

    const size_t MB = 1u<<20;
    char* base = (char*)d_ws;
    const bool big = (ws_size >= (size_t)96*MB);
    const int CHr = big ? 2048 : 1024;
    // ---- persistent (21 MB) ----
    float* q_attn = (float*)base;
    float* kgv    = q_attn + 1024;
    float* vgv    = kgv + 1024;
    int*   knn    = (int*)(base + 16*1024);
    short* wksb = (short*)(base + 1*MB);
    short* wvsb = wksb + 262144;
    short* wd2b = wvsb + 262144;
    short* wg1b = wd2b + 262144;
    short* wg2b = wg1b + 262144;
    short* dch = (short*)(base + 1*MB);         short* dcl = dch + 262144;
    short* d0h = dcl + 262144;                  short* d0l = d0h + 262144;
    short* d1h = d0l + 262144;                  short* d1l = d1h + 262144;
    short* lath = (short*)(base + 5*MB);
    short* latl = (short*)(base + 13*MB);
    // ---- transient T ----
    char* T = base + 21*MB;
    short* ak_bf = (short*)T;                                  // 4 MB
    short* av_bf = (short*)(T + 4*MB);                         // 4 MB
    short* posb  = (short*)(T + 8*MB);                         // CHr*8*512*2
    char*  ybp   = (char*)posb + (size_t)CHr*8*512*2;
    short* yb    = (short*)ybp;                                // CHr*9*512*2
    short* attn_preb = (short*)(ybp + (size_t)CHr*9*512*2);    // CHr*9*512*2
    short* af_bf = (short*)(T + 8*MB);                         // phase A overlay
    short* peA  = attn_preb;
    short* g1A  = attn_preb;
    short* nrh = (short*)T;            short* nrl = (short*)(T + 8*MB);
    short* hdh = (short*)(T + 16*MB);  short* hdl = (short*)(T + 24*MB);
    short* dwH = (short*)(base + 81*MB);
    short* dwL = dwH + (size_t)15*262144;
    if (!big && (size_t)(55*MB) > ws_size) return;

    proj_small<<<dim3(6), dim3(256), 0, stream>>>(gf, w_qs, w_kg, w_vg, q_attn, kgv, vgv);
    knn_kernel<<<dim3(1024), dim3(256), 0, stream>>>(xyz_q, axyz, knn);

    cvt_bf16<<<dim3(1024), dim3(256), 0, stream>>>(afeat, af_bf);
    prep_w5<<<dim3(640), dim3(256), 0, stream>>>(w_ks, w_vs, d2_w, g1_w, g2_w,
                                                 wksb, wvsb, wd2b, wg1b, wg2b);
    if (big) {
        // hoisted: input-only, writes untouched region; off the decoder critical path
        prep_w3all<<<dim3(1920), dim3(256), 0, stream>>>(fc_c_w, blk0_w, blk1_w, dwH, dwL);
    }
    gemm1b<0><<<dim3(8, 32), dim3(256), 0, stream>>>(af_bf, wksb, nullptr, ak_bf);
    gemm1b<0><<<dim3(8, 32), dim3(256), 0, stream>>>(af_bf, wvsb, nullptr, av_bf);

    for (int qbase = 0; qbase < B*NQ; qbase += CHr) {
        pe_make<<<dim3(CHr*8/4), dim3(256), 0, stream>>>(xyz_q, axyz, knn, d1_w, d1_b, peA, qbase);
        if (big) {
            // 128x128 m97-shape at >=2 blocks/CU (grids 512/576)
            gemm1c<0><<<dim3(4, CHr*8/128), dim3(256), 0, stream>>>(peA, wd2b, d2_b, posb);
            g1_make<<<dim3(CHr*9/4), dim3(256), 0, stream>>>(q_attn, kgv, ak_bf, posb, knn, g1A, qbase);
            gemm1c<1><<<dim3(4, CHr*9/128), dim3(256), 0, stream>>>(g1A, wg1b, g1_b, yb);
            gemm1c<0><<<dim3(4, CHr*9/128), dim3(256), 0, stream>>>(yb, wg2b, g2_b, attn_preb);
        } else {
            gemm1b<0><<<dim3(8, CHr*8/128), dim3(256), 0, stream>>>(peA, wd2b, d2_b, posb);
            g1_make<<<dim3(CHr*9/4), dim3(256), 0, stream>>>(q_attn, kgv, ak_bf, posb, knn, g1A, qbase);
            gemm1b<1><<<dim3(8, CHr*9/128), dim3(256), 0, stream>>>(g1A, wg1b, g1_b, yb);
            gemm1b<0><<<dim3(8, CHr*9/128), dim3(256), 0, stream>>>(yb, wg2b, g2_b, attn_preb);
        }
        softmax_agg<<<dim3(CHr), dim3(256), 0, stream>>>(attn_preb, posb, av_bf, vgv, knn, lath, latl, qbase);
    }

    pe_fc<<<dim3(512), dim3(256), 0, stream>>>(xyz_q, fc_p_w, fc_p_b, out);
    if (big) {
        for (int i=0;i<5;i++) {
            const float* cb  = fc_c_b + (size_t)i*512;
            const float* b0b = blk0_b + (size_t)i*512;
            const float* b1b = blk1_b + (size_t)i*512;
            short* ch = dwH + (size_t)(i*3+0)*262144; short* cl = dwL + (size_t)(i*3+0)*262144;
            short* h0 = dwH + (size_t)(i*3+1)*262144; short* l0 = dwL + (size_t)(i*3+1)*262144;
            short* h1 = dwH + (size_t)(i*3+2)*262144; short* l1 = dwL + (size_t)(i*3+2)*262144;
            gemm3b<2,0,1><<<dim3(8,64), dim3(256), 0, stream>>>(lath, latl, ch, cl, cb, out, out, nrh, nrl);
            gemm3b<1,1,0><<<dim3(8,64), dim3(256), 0, stream>>>(nrh, nrl, h0, l0, b0b, nullptr, nullptr, hdh, hdl);
            gemm3b<0,0,1><<<dim3(8,64), dim3(256), 0, stream>>>(hdh, hdl, h1, l1, b1b, out, out, nullptr, nullptr);
        }
    } else {
        for (int i=0;i<5;i++) {
            const float* cw  = fc_c_w + (size_t)i*512*512;
            const float* cb  = fc_c_b + (size_t)i*512;
            const float* b0w = blk0_w + (size_t)i*512*512;
            const float* b0b = blk0_b + (size_t)i*512;
            const float* b1w = blk1_w + (size_t)i*512*512;
            const float* b1b = blk1_b + (size_t)i*512;
            prep_w3<<<dim3(384), dim3(256), 0, stream>>>(cw, b0w, b1w, dch, dcl, d0h, d0l, d1h, d1l);
            gemm3b<2,0,1><<<dim3(8,64), dim3(256), 0, stream>>>(lath, latl, dch, dcl, cb, out, out, nrh, nrl);
            gemm3b<1,1,0><<<dim3(8,64), dim3(256), 0, stream>>>(nrh, nrl, d0h, d0l, b0b, nullptr, nullptr, hdh, hdl);
            gemm3b<0,0,1><<<dim3(8,64), dim3(256), 0, stream>>>(hdh, hdl, d1h, d1l, b1b, out, out, nullptr, nullptr);
        }
    }
}